// Round 5
// baseline (301.537 us; speedup 1.0000x reference)
//
#include <hip/hip_runtime.h>

#define NHEADS 16
#define DEMBED 1024
#define DCROSS 768
#define DHEAD  64
#define BATCH  4
#define SLEN   2048
#define MROWS  (BATCH * SLEN)   // 8192

using bf16   = __bf16;
using bf16x8 = __attribute__((ext_vector_type(8))) __bf16;
using bf16x4 = __attribute__((ext_vector_type(4))) __bf16;
using bf16x2 = __attribute__((ext_vector_type(2))) __bf16;
using f32x4  = __attribute__((ext_vector_type(4))) float;
using f32x16 = __attribute__((ext_vector_type(16))) float;

__device__ __forceinline__ f32x4 mfma_bf16(bf16x8 a, bf16x8 b, f32x4 c) {
    return __builtin_amdgcn_mfma_f32_16x16x32_bf16(a, b, c, 0, 0, 0);
}
__device__ __forceinline__ f32x16 mfma32(bf16x8 a, bf16x8 b, f32x16 c) {
    return __builtin_amdgcn_mfma_f32_32x32x16_bf16(a, b, c, 0, 0, 0);
}

// async global->LDS, 16B per lane; lds dest = wave-uniform base + lane*16
__device__ __forceinline__ void gl2lds16(const void* g, void* l) {
    __builtin_amdgcn_global_load_lds(
        (const __attribute__((address_space(1))) void*)g,
        (__attribute__((address_space(3))) void*)l, 16, 0, 0);
}

// ---------------------------------------------------------------- prep (one kernel)
struct PrepArgs {
    const float* wsrc[4]; bf16* wdst[4]; int wK[4];
    const float *x, *y; bf16 *xb, *yb;
};
#define NTRB 4096
__global__ void prep_all(PrepArgs a) {
    const int bid = blockIdx.x;
    const int tid = threadIdx.x;
    if (bid < NTRB) {
        __shared__ float tile[32][33];
        const int which = bid >> 10, rem = bid & 1023;
        const int K = a.wK[which], N = DEMBED;
        const int n0 = (rem & 31) * 32, k0 = (rem >> 5) * 32;
        if (k0 >= K) return;
        const float* W = a.wsrc[which];
        bf16* Wt = a.wdst[which];
        const int tx = tid & 31, ty = tid >> 5;
#pragma unroll
        for (int i = 0; i < 32; i += 8)
            tile[ty + i][tx] = W[(size_t)(k0 + ty + i) * N + n0 + tx];
        __syncthreads();
#pragma unroll
        for (int i = 0; i < 32; i += 8)
            Wt[(size_t)(n0 + ty + i) * K + k0 + tx] = (bf16)tile[tx][ty + i];
    } else {
        const int n4x = MROWS * DEMBED / 4;
        const int n4y = MROWS * DCROSS / 4;
        int i = (bid - NTRB) * 256 + tid;
        const float* src; bf16* dst; int j;
        if (i < n4x) { src = a.x; dst = a.xb; j = i; }
        else { j = i - n4x; if (j >= n4y) return; src = a.y; dst = a.yb; }
        float4 v = ((const float4*)src)[j];
        bf16x4 o = { (bf16)v.x, (bf16)v.y, (bf16)v.z, (bf16)v.w };
        ((bf16x4*)dst)[j] = o;
    }
}

// ---------------------------------------------------------------- fused QKV GEMM (r11: 256x256 tile)
// 512 threads, 8 waves (2M x 4N), per-wave 128x64 output (acc 8x4).
// One gl2lds sweep = 8 waves x 1024 B = 8192 B = 64 rows; 4 sweeps = 256 rows.
// blocks (after XCD swizzle): [0,128) Q, [128,256) K, [256,384) V^T.
struct QkvArgs {
    const bf16 *xb, *yb, *Wqt, *Wkt, *Wvt;
    const float *bq, *bk, *bv;
    bf16 *Qb, *Kb, *Vt;
    float qscale;
};
__global__ __launch_bounds__(512, 2) void gemm_qkv(QkvArgs a) {
    __shared__ bf16 As[256 * 64];   // 32 KB
    __shared__ bf16 Bs[256 * 64];   // 32 KB
    const int rb = blockIdx.x;
    const int bid = (rb & 7) * 48 + (rb >> 3);   // XCD swizzle, 384 % 8 == 0
    const int cls = bid >> 7;                    // 0=Q 1=K 2=V
    const int t = bid & 127;
    const bf16 *A, *Bt;
    const float* bias;
    int K, m0, n0;
    if (cls == 0)      { m0 = (t >> 2) << 8; n0 = (t & 3) << 8;
                         A = a.xb;  Bt = a.Wqt; bias = a.bq; K = DEMBED; }
    else if (cls == 1) { m0 = (t >> 2) << 8; n0 = (t & 3) << 8;
                         A = a.yb;  Bt = a.Wkt; bias = a.bk; K = DCROSS; }
    else               { m0 = (t >> 5) << 8; n0 = (t & 31) << 8;
                         A = a.Wvt; Bt = a.yb;  bias = a.bv; K = DCROSS; }

    const int tid  = threadIdx.x;
    const int wave = tid >> 6, lane = tid & 63;
    const int quad = lane >> 4, l15 = lane & 15;
    const int wr = wave >> 2, wcn = wave & 3;    // 2M x 4N wave grid

    const int srow = tid >> 3;                   // 0..63 (4 sweeps cover 256 rows)
    const int gcol = ((tid & 7) ^ (srow & 7)) * 8;
    char* ldsA0 = (char*)As + wave * 1024;
    char* ldsB0 = (char*)Bs + wave * 1024;
    const bf16* gA0 = A + (size_t)(m0 + srow) * K + gcol;
    const bf16* gB0 = Bt + (size_t)(n0 + srow) * K + gcol;

    const int sw = l15 & 7;

    f32x4 acc[8][4] = {};

    for (int kt = 0; kt < K; kt += 64) {
        __syncthreads();
#pragma unroll
        for (int c = 0; c < 4; c++)
            gl2lds16(gA0 + (size_t)c * 64 * K + kt, ldsA0 + c * 8192);
#pragma unroll
        for (int c = 0; c < 4; c++)
            gl2lds16(gB0 + (size_t)c * 64 * K + kt, ldsB0 + c * 8192);
        __syncthreads();

#pragma unroll
        for (int kg = 0; kg < 2; kg++) {
            bf16x8 bfr[4];
#pragma unroll
            for (int i = 0; i < 4; i++)
                bfr[i] = *(const bf16x8*)((const char*)Bs +
                         (wcn * 64 + i * 16 + l15) * 128 + (((kg * 4 + quad) ^ sw) * 16));
#pragma unroll
            for (int fr = 0; fr < 8; fr++) {
                bf16x8 af = *(const bf16x8*)((const char*)As +
                         (wr * 128 + fr * 16 + l15) * 128 + (((kg * 4 + quad) ^ sw) * 16));
#pragma unroll
                for (int fc = 0; fc < 4; fc++)
                    acc[fr][fc] = mfma_bf16(af, bfr[fc], acc[fr][fc]);
            }
        }
    }

    if (cls < 2) {
        bf16* Cout = (cls == 0) ? a.Qb : a.Kb;
        const float alpha = (cls == 0) ? a.qscale : 1.0f;
#pragma unroll
        for (int fr = 0; fr < 8; fr++) {
            int row = m0 + wr * 128 + fr * 16 + quad * 4;
#pragma unroll
            for (int fc = 0; fc < 4; fc++) {
                int col = n0 + wcn * 64 + fc * 16 + l15;
                float bv = bias[col];
#pragma unroll
                for (int r = 0; r < 4; r++)
                    Cout[(size_t)(row + r) * DEMBED + col] =
                        (bf16)((acc[fr][fc][r] + bv) * alpha);
            }
        }
    } else {
        const int b = n0 >> 11;
        const size_t bbase = (size_t)b * DEMBED * SLEN;
#pragma unroll
        for (int fr = 0; fr < 8; fr++) {
            int row = m0 + wr * 128 + fr * 16 + quad * 4;
#pragma unroll
            for (int fc = 0; fc < 4; fc++) {
                int col = n0 + wcn * 64 + fc * 16 + l15;
                int s = col & (SLEN - 1);
#pragma unroll
                for (int r = 0; r < 4; r++)
                    a.Vt[bbase + (size_t)(row + r) * SLEN + s] =
                        (bf16)(acc[fr][fc][r] + bias[row + r]);
            }
        }
    }
}

// ---------------------------------------------------------------- O GEMM (r11: 256x128 tile)
// 512 threads, 8 waves (4M x 2N), per-wave 64x64. Grid 32x8 = 256 blocks.
__global__ __launch_bounds__(512, 2) void gemm_o(const bf16* __restrict__ A,
                                                 const bf16* __restrict__ Bt,
                                                 const float* __restrict__ bias,
                                                 float* __restrict__ Cout) {
    const int K = DEMBED, N = DEMBED;
    __shared__ bf16 As[256 * 64];   // 32 KB
    __shared__ bf16 Bs[128 * 64];   // 16 KB
    const int tid  = threadIdx.x;
    const int wave = tid >> 6, lane = tid & 63;
    const int quad = lane >> 4, l15 = lane & 15;
    const int m0 = blockIdx.x * 256, n0 = blockIdx.y * 128;
    const int wr = wave >> 1, wcn = wave & 1;    // 4M x 2N wave grid

    const int srow = tid >> 3;
    const int gcol = ((tid & 7) ^ (srow & 7)) * 8;
    char* ldsA0 = (char*)As + wave * 1024;
    char* ldsB0 = (char*)Bs + wave * 1024;
    const bf16* gA0 = A + (size_t)(m0 + srow) * K + gcol;
    const bf16* gB0 = Bt + (size_t)(n0 + srow) * K + gcol;

    const int sw = l15 & 7;

    f32x4 acc[4][4] = {};

    for (int kt = 0; kt < K; kt += 64) {
        __syncthreads();
#pragma unroll
        for (int c = 0; c < 4; c++)
            gl2lds16(gA0 + (size_t)c * 64 * K + kt, ldsA0 + c * 8192);
#pragma unroll
        for (int c = 0; c < 2; c++)
            gl2lds16(gB0 + (size_t)c * 64 * K + kt, ldsB0 + c * 8192);
        __syncthreads();

#pragma unroll
        for (int kg = 0; kg < 2; kg++) {
            bf16x8 bfr[4];
#pragma unroll
            for (int i = 0; i < 4; i++)
                bfr[i] = *(const bf16x8*)((const char*)Bs +
                         (wcn * 64 + i * 16 + l15) * 128 + (((kg * 4 + quad) ^ sw) * 16));
#pragma unroll
            for (int fr = 0; fr < 4; fr++) {
                bf16x8 af = *(const bf16x8*)((const char*)As +
                         (wr * 64 + fr * 16 + l15) * 128 + (((kg * 4 + quad) ^ sw) * 16));
#pragma unroll
                for (int fc = 0; fc < 4; fc++)
                    acc[fr][fc] = mfma_bf16(af, bfr[fc], acc[fr][fc]);
            }
        }
    }

#pragma unroll
    for (int fr = 0; fr < 4; fr++) {
        int row = m0 + wr * 64 + fr * 16 + quad * 4;
#pragma unroll
        for (int fc = 0; fc < 4; fc++) {
            int col = n0 + wcn * 64 + fc * 16 + l15;
            float bv = bias[col];
#pragma unroll
            for (int r = 0; r < 4; r++)
                Cout[(size_t)(row + r) * N + col] = acc[fr][fc][r] + bv;
        }
    }
}

// ---------------------------------------------------------------- attention (r9, unchanged)
__global__ __launch_bounds__(128, 2) void attn(const bf16* __restrict__ Q,
                                               const bf16* __restrict__ K,
                                               const bf16* __restrict__ Vt,
                                               bf16* __restrict__ O) {
    __shared__ bf16 KsA[2][64 * 64];     // [buf][key][d]   XOR-swizzled slots
    __shared__ bf16 VsA[2][64 * 64];     // [buf][d][key]   XOR-swizzled slots

    const int tid  = threadIdx.x;
    const int wave = tid >> 6, lane = tid & 63;
    const int l31  = lane & 31, H = lane >> 5;
    const int bh = blockIdx.x, b = bh >> 4, h = bh & 15;
    const size_t rowbase = (size_t)b * SLEN;
    const int qb = blockIdx.y * 128 + wave * 64;   // 64 q-rows per wave
    const int hc = h * DHEAD;

    // Q fragments (B-operand of 32x32x16): lane holds Q[q=l31][d=ks*16+H*8+j]
    bf16x8 qf[2][4];
#pragma unroll
    for (int qs = 0; qs < 2; qs++)
#pragma unroll
        for (int ks = 0; ks < 4; ks++)
            qf[qs][ks] = *(const bf16x8*)(Q + (rowbase + qb + qs * 32 + l31) * DEMBED
                                          + hc + ks * 16 + H * 8);

    f32x16 o00 = {}, o01 = {}, o10 = {}, o11 = {};   // [qs][dg]
    float lsv0 = 0.0f, lsv1 = 0.0f;

    const bf16* Kbase = K + rowbase * DEMBED + hc;
    const bf16* Vbase = Vt + (size_t)bh * DHEAD * SLEN;

    const int grow = tid >> 3;                         // 0..15
    const int xcol = ((tid & 7) ^ (grow & 7)) * 8;
    const bf16* gK = Kbase + (size_t)grow * DEMBED + xcol;
    const bf16* gV = Vbase + (size_t)grow * SLEN + xcol;

    const int swz = l31 & 7;             // row XOR for reads

    auto STAGE = [&](int buf, int kb) {
        char* lk = (char*)KsA + buf * 8192 + wave * 1024;
        char* lv = (char*)VsA + buf * 8192 + wave * 1024;
#pragma unroll
        for (int c = 0; c < 4; c++) {
            gl2lds16(gK + (size_t)(kb + c * 16) * DEMBED, lk + c * 2048);
            gl2lds16(gV + (size_t)(c * 16) * SLEN + kb,   lv + c * 2048);
        }
    };

    auto expPack = [&](const f32x16& s, int* c, float& l) {
#pragma unroll
        for (int t = 0; t < 8; t++) {
            float e0 = __builtin_amdgcn_exp2f(s[2 * t]);
            float e1 = __builtin_amdgcn_exp2f(s[2 * t + 1]);
            l += e0 + e1;
            union { bf16x2 h; int i; } p;
            p.h[0] = (bf16)e0; p.h[1] = (bf16)e1;
            c[t] = p.i;
        }
    };

    auto pvpair = [&](const int* cc, int ksl, bf16x8 vf0, bf16x8 vf1,
                      f32x16& oo0, f32x16& oo1) {
        auto w0 = __builtin_amdgcn_permlane32_swap(cc[4 * ksl + 0],
                                                   cc[4 * ksl + 2], false, false);
        auto w1 = __builtin_amdgcn_permlane32_swap(cc[4 * ksl + 1],
                                                   cc[4 * ksl + 3], false, false);
        union { int i[4]; bf16x8 v; } ap;
        ap.i[0] = w0[0]; ap.i[1] = w1[0]; ap.i[2] = w0[1]; ap.i[3] = w1[1];
        __builtin_amdgcn_s_setprio(1);
        oo0 = mfma32(ap.v, vf0, oo0);
        oo1 = mfma32(ap.v, vf1, oo1);
        __builtin_amdgcn_s_setprio(0);
    };

    STAGE(0, 0);
    __syncthreads();

    int cur = 0;
    for (int kb = 0; kb < SLEN; kb += 64) {
        if (kb + 64 < SLEN) STAGE(cur ^ 1, kb + 64);

        const char* Kbuf = (const char*)KsA + cur * 8192;
        const char* Vbuf = (const char*)VsA + cur * 8192;

        // ---- QK^T (swapped): s = mfma(A=K, B=Q) -> S^T[key][q]
        f32x16 s00 = {}, s01 = {}, s10 = {}, s11 = {};   // [qs][keyhalf]
        __builtin_amdgcn_s_setprio(1);
#pragma unroll
        for (int ks = 0; ks < 4; ks++) {
            const int slot = ((2 * ks + H) ^ swz) * 16;
            bf16x8 kf0 = *(const bf16x8*)(Kbuf + l31 * 128 + slot);
            bf16x8 kf1 = *(const bf16x8*)(Kbuf + (32 + l31) * 128 + slot);
            s00 = mfma32(kf0, qf[0][ks], s00);
            s01 = mfma32(kf1, qf[0][ks], s01);
            s10 = mfma32(kf0, qf[1][ks], s10);
            s11 = mfma32(kf1, qf[1][ks], s11);
        }
        __builtin_amdgcn_s_setprio(0);

        int cA0[8], cA1[8], cB0[8], cB1[8];

        expPack(s00, cA0, lsv0);           // E-A (feeds PV ks=0,1)
        expPack(s10, cA1, lsv1);

#pragma unroll
        for (int ks = 0; ks < 4; ks++) {
            if (ks == 1) expPack(s01, cB0, lsv0);   // hides under ks=0 PV
            if (ks == 2) expPack(s11, cB1, lsv1);   // hides under ks=1 PV
            const int slot = ((2 * ks + H) ^ swz) * 16;
            bf16x8 vf0 = *(const bf16x8*)(Vbuf + l31 * 128 + slot);
            bf16x8 vf1 = *(const bf16x8*)(Vbuf + (32 + l31) * 128 + slot);
            const int* u0 = (ks < 2) ? cA0 : cB0;
            const int* u1 = (ks < 2) ? cA1 : cB1;
            const int ksl = ks & 1;
            pvpair(u0, ksl, vf0, vf1, o00, o01);
            pvpair(u1, ksl, vf0, vf1, o10, o11);
        }

        __syncthreads();   // drains prefetch (vmcnt0) + protects buffer reuse
        cur ^= 1;
    }

    lsv0 += __shfl_xor(lsv0, 32);
    lsv1 += __shfl_xor(lsv1, 32);
    float inv0 = 1.0f / lsv0;
    float inv1 = 1.0f / lsv1;
#pragma unroll
    for (int r = 0; r < 16; r++) {
        const int ql = (r & 3) + 8 * (r >> 2) + 4 * H;
        float iv0 = __shfl(inv0, ql);
        float iv1 = __shfl(inv1, ql);
        O[(rowbase + qb + ql) * DEMBED + hc + l31]      = (bf16)(o00[r] * iv0);
        O[(rowbase + qb + ql) * DEMBED + hc + 32 + l31] = (bf16)(o01[r] * iv0);
        O[(rowbase + qb + 32 + ql) * DEMBED + hc + l31]      = (bf16)(o10[r] * iv1);
        O[(rowbase + qb + 32 + ql) * DEMBED + hc + 32 + l31] = (bf16)(o11[r] * iv1);
    }
}

// ---------------------------------------------------------------- launch
extern "C" void kernel_launch(void* const* d_in, const int* in_sizes, int n_in,
                              void* d_out, int out_size, void* d_ws, size_t ws_size,
                              hipStream_t stream) {
    const float* x  = (const float*)d_in[0];
    const float* y  = (const float*)d_in[1];
    const float* Wq = (const float*)d_in[2];
    const float* bq = (const float*)d_in[3];
    const float* Wk = (const float*)d_in[4];
    const float* bk = (const float*)d_in[5];
    const float* Wv = (const float*)d_in[6];
    const float* bv = (const float*)d_in[7];
    const float* Wo = (const float*)d_in[8];
    const float* bo = (const float*)d_in[9];
    float* out = (float*)d_out;

    char* ws = (char*)d_ws;
    size_t off = 0;
    auto alloc = [&](size_t bytes) {
        void* p = ws + off;
        off += (bytes + 255) & ~(size_t)255;
        return p;
    };
    bf16* xb  = (bf16*)alloc((size_t)MROWS * DEMBED * 2);
    bf16* yb  = (bf16*)alloc((size_t)MROWS * DCROSS * 2);
    bf16* Wqt = (bf16*)alloc((size_t)DEMBED * DEMBED * 2);
    bf16* Wkt = (bf16*)alloc((size_t)DEMBED * DCROSS * 2);
    bf16* Wvt = (bf16*)alloc((size_t)DEMBED * DCROSS * 2);
    bf16* Wot = (bf16*)alloc((size_t)DEMBED * DEMBED * 2);
    bf16* Qb  = (bf16*)alloc((size_t)MROWS * DEMBED * 2);
    bf16* Kb  = (bf16*)alloc((size_t)MROWS * DEMBED * 2);
    bf16* Vtb = (bf16*)alloc((size_t)MROWS * DEMBED * 2);  // V^T per head
    bf16* Ab  = (bf16*)alloc((size_t)MROWS * DEMBED * 2);
    if (off > ws_size) return;

    {
        PrepArgs a;
        a.wsrc[0] = Wq; a.wdst[0] = Wqt; a.wK[0] = DEMBED;
        a.wsrc[1] = Wk; a.wdst[1] = Wkt; a.wK[1] = DCROSS;
        a.wsrc[2] = Wv; a.wdst[2] = Wvt; a.wK[2] = DCROSS;
        a.wsrc[3] = Wo; a.wdst[3] = Wot; a.wK[3] = DEMBED;
        a.x = x; a.y = y; a.xb = xb; a.yb = yb;
        int ncvt = (MROWS * DEMBED / 4 + MROWS * DCROSS / 4 + 255) / 256;
        prep_all<<<NTRB + ncvt, 256, 0, stream>>>(a);
    }

    {
        QkvArgs a;
        a.xb = xb; a.yb = yb; a.Wqt = Wqt; a.Wkt = Wkt; a.Wvt = Wvt;
        a.bq = bq; a.bk = bk; a.bv = bv;
        a.Qb = Qb; a.Kb = Kb; a.Vt = Vtb;
        a.qscale = 0.125f * 1.4426950408889634f;   // 1/sqrt(64) * log2(e)
        gemm_qkv<<<384, 512, 0, stream>>>(a);
    }

    attn<<<dim3(BATCH * NHEADS, SLEN / 128), 128, 0, stream>>>(Qb, Kb, Vtb, Ab);

    gemm_o<<<dim3(MROWS / 256, DEMBED / 128), 512, 0, stream>>>(Ab, Wot, bo, out);
}

// Round 6
// 298.469 us; speedup vs baseline: 1.0103x; 1.0103x over previous
//
#include <hip/hip_runtime.h>

#define NHEADS 16
#define DEMBED 1024
#define DCROSS 768
#define DHEAD  64
#define BATCH  4
#define SLEN   2048
#define MROWS  (BATCH * SLEN)   // 8192

using bf16   = __bf16;
using bf16x8 = __attribute__((ext_vector_type(8))) __bf16;
using bf16x4 = __attribute__((ext_vector_type(4))) __bf16;
using bf16x2 = __attribute__((ext_vector_type(2))) __bf16;
using f32x4  = __attribute__((ext_vector_type(4))) float;
using f32x16 = __attribute__((ext_vector_type(16))) float;

__device__ __forceinline__ f32x4 mfma_bf16(bf16x8 a, bf16x8 b, f32x4 c) {
    return __builtin_amdgcn_mfma_f32_16x16x32_bf16(a, b, c, 0, 0, 0);
}
__device__ __forceinline__ f32x16 mfma32(bf16x8 a, bf16x8 b, f32x16 c) {
    return __builtin_amdgcn_mfma_f32_32x32x16_bf16(a, b, c, 0, 0, 0);
}

// async global->LDS, 16B per lane; lds dest = wave-uniform base + lane*16
__device__ __forceinline__ void gl2lds16(const void* g, void* l) {
    __builtin_amdgcn_global_load_lds(
        (const __attribute__((address_space(1))) void*)g,
        (__attribute__((address_space(3))) void*)l, 16, 0, 0);
}

// ---------------------------------------------------------------- prep (one kernel)
struct PrepArgs {
    const float* wsrc[4]; bf16* wdst[4]; int wK[4];
    const float *x, *y; bf16 *xb, *yb;
};
#define NTRB 4096
__global__ void prep_all(PrepArgs a) {
    const int bid = blockIdx.x;
    const int tid = threadIdx.x;
    if (bid < NTRB) {
        __shared__ float tile[32][33];
        const int which = bid >> 10, rem = bid & 1023;
        const int K = a.wK[which], N = DEMBED;
        const int n0 = (rem & 31) * 32, k0 = (rem >> 5) * 32;
        if (k0 >= K) return;
        const float* W = a.wsrc[which];
        bf16* Wt = a.wdst[which];
        const int tx = tid & 31, ty = tid >> 5;
#pragma unroll
        for (int i = 0; i < 32; i += 8)
            tile[ty + i][tx] = W[(size_t)(k0 + ty + i) * N + n0 + tx];
        __syncthreads();
#pragma unroll
        for (int i = 0; i < 32; i += 8)
            Wt[(size_t)(n0 + ty + i) * K + k0 + tx] = (bf16)tile[tx][ty + i];
    } else {
        const int n4x = MROWS * DEMBED / 4;
        const int n4y = MROWS * DCROSS / 4;
        int i = (bid - NTRB) * 256 + tid;
        const float* src; bf16* dst; int j;
        if (i < n4x) { src = a.x; dst = a.xb; j = i; }
        else { j = i - n4x; if (j >= n4y) return; src = a.y; dst = a.yb; }
        float4 v = ((const float4*)src)[j];
        bf16x4 o = { (bf16)v.x, (bf16)v.y, (bf16)v.z, (bf16)v.w };
        ((bf16x4*)dst)[j] = o;
    }
}

// ---------------------------------------------------------------- fused QKV GEMM (r12)
// 256x128 tile, 512 threads / 8 waves (4M x 2N, per-wave 64x64 = the proven
// 128^2 wave code). TRIPLE-buffered LDS (96+48 KB) with counted vmcnt (T4):
// tile t+2 staged each iter, s_waitcnt vmcnt(12) drains exactly tile t's own
// 6 loads -> loads span two full compute phases, no vmcnt(0) in main loop.
// Grid 768 = 3 exact waves over 256 CUs; bijective XCD swizzle (768%8==0).
struct QkvArgs {
    const bf16 *xb, *yb, *Wqt, *Wkt, *Wvt;
    const float *bq, *bk, *bv;
    bf16 *Qb, *Kb, *Vt;
    float qscale;
};
__global__ __launch_bounds__(512, 2) void gemm_qkv(QkvArgs a) {
    __shared__ bf16 As[3 * 256 * 64];   // 96 KB (3 x 32 KB A tiles)
    __shared__ bf16 Bs[3 * 128 * 64];   // 48 KB (3 x 16 KB B tiles)
    const int rb  = blockIdx.x;
    const int bid = (rb & 7) * 96 + (rb >> 3);   // XCD swizzle, 768 % 8 == 0
    const int cls = bid >> 8;                    // 0=Q 1=K 2=V
    const int tt  = bid & 255;
    const bf16 *A, *Bt;
    const float* bias;
    int K, m0, n0;
    if (cls == 0)      { m0 = (tt >> 3) << 8; n0 = (tt & 7) << 7;
                         A = a.xb;  Bt = a.Wqt; bias = a.bq; K = DEMBED; }
    else if (cls == 1) { m0 = (tt >> 3) << 8; n0 = (tt & 7) << 7;
                         A = a.yb;  Bt = a.Wkt; bias = a.bk; K = DCROSS; }
    else               { m0 = (tt >> 6) << 8; n0 = (tt & 63) << 7;
                         A = a.Wvt; Bt = a.yb;  bias = a.bv; K = DCROSS; }

    const int tid  = threadIdx.x;
    const int wave = tid >> 6, lane = tid & 63;
    const int quad = lane >> 4, l15 = lane & 15;
    const int wr = wave >> 1, wc = wave & 1;     // 4M x 2N wave grid

    const int srow = tid >> 3;                   // 0..63 rows per sweep
    const int gcol = ((tid & 7) ^ (srow & 7)) * 8;
    char* ldsA = (char*)As + wave * 1024;
    char* ldsB = (char*)Bs + wave * 1024;
    const bf16* gA0 = A + (size_t)(m0 + srow) * K + gcol;
    const bf16* gB0 = Bt + (size_t)(n0 + srow) * K + gcol;

    const int sw = l15 & 7;
    const int NT = K >> 6;                       // 16 (Q) or 12 (K/V)

    // one STAGE = 6 gl2lds per wave: A tile (4 x 64 rows) + B tile (2 x 64 rows)
    auto STAGE = [&](int buf, int kt) {
        char* la = ldsA + buf * 32768;
        char* lb = ldsB + buf * 16384;
#pragma unroll
        for (int c = 0; c < 4; c++)
            gl2lds16(gA0 + (size_t)c * 64 * K + kt, la + c * 8192);
#pragma unroll
        for (int c = 0; c < 2; c++)
            gl2lds16(gB0 + (size_t)c * 64 * K + kt, lb + c * 8192);
    };

    f32x4 acc[4][4] = {};

    STAGE(0, 0);
    STAGE(1, 64);

    int buf = 0;
    for (int t2 = 0; t2 < NT; ++t2) {
        if (t2 + 2 < NT) STAGE(buf == 0 ? 2 : buf - 1, (t2 + 2) << 6);
        const int rem = NT - 1 - t2;
        if (rem >= 2)      asm volatile("s_waitcnt vmcnt(12)");
        else if (rem == 1) asm volatile("s_waitcnt vmcnt(6)");
        else               asm volatile("s_waitcnt vmcnt(0)");
        __builtin_amdgcn_sched_barrier(0);
        __builtin_amdgcn_s_barrier();            // tile t visible block-wide
        __builtin_amdgcn_sched_barrier(0);

        const char* Ab = (const char*)As + buf * 32768;
        const char* Bb = (const char*)Bs + buf * 16384;
#pragma unroll
        for (int kg = 0; kg < 2; kg++) {
            bf16x8 af[4], bfr[4];
#pragma unroll
            for (int i = 0; i < 4; i++)
                bfr[i] = *(const bf16x8*)(Bb +
                         (wc * 64 + i * 16 + l15) * 128 + (((kg * 4 + quad) ^ sw) * 16));
#pragma unroll
            for (int i = 0; i < 4; i++)
                af[i] = *(const bf16x8*)(Ab +
                         (wr * 64 + i * 16 + l15) * 128 + (((kg * 4 + quad) ^ sw) * 16));
            __builtin_amdgcn_s_setprio(1);
#pragma unroll
            for (int fr = 0; fr < 4; fr++)
#pragma unroll
                for (int fc = 0; fc < 4; fc++)
                    acc[fr][fc] = mfma_bf16(af[fr], bfr[fc], acc[fr][fc]);
            __builtin_amdgcn_s_setprio(0);
        }

        asm volatile("s_waitcnt lgkmcnt(0)");
        __builtin_amdgcn_sched_barrier(0);
        __builtin_amdgcn_s_barrier();            // all reads of buf done
        __builtin_amdgcn_sched_barrier(0);
        buf = (buf == 2) ? 0 : buf + 1;
    }

    if (cls < 2) {
        bf16* Cout = (cls == 0) ? a.Qb : a.Kb;
        const float alpha = (cls == 0) ? a.qscale : 1.0f;
#pragma unroll
        for (int fr = 0; fr < 4; fr++) {
            int row = m0 + wr * 64 + fr * 16 + quad * 4;
#pragma unroll
            for (int fc = 0; fc < 4; fc++) {
                int col = n0 + wc * 64 + fc * 16 + l15;
                float bv = bias[col];
#pragma unroll
                for (int r = 0; r < 4; r++)
                    Cout[(size_t)(row + r) * DEMBED + col] =
                        (bf16)((acc[fr][fc][r] + bv) * alpha);
            }
        }
    } else {
        const int b = n0 >> 11;
        const size_t bbase = (size_t)b * DEMBED * SLEN;
#pragma unroll
        for (int fr = 0; fr < 4; fr++) {
            int row = m0 + wr * 64 + fr * 16 + quad * 4;
#pragma unroll
            for (int fc = 0; fc < 4; fc++) {
                int col = n0 + wc * 64 + fc * 16 + l15;
                int s = col & (SLEN - 1);
#pragma unroll
                for (int r = 0; r < 4; r++)
                    a.Vt[bbase + (size_t)(row + r) * SLEN + s] =
                        (bf16)(acc[fr][fc][r] + bias[row + r]);
            }
        }
    }
}

// ---------------------------------------------------------------- O GEMM (r6 128^2, reverted)
__global__ __launch_bounds__(256, 3) void gemm_o(const bf16* __restrict__ A,
                                                 const bf16* __restrict__ Bt,
                                                 const float* __restrict__ bias,
                                                 float* __restrict__ Cout) {
    const int K = DEMBED, N = DEMBED;
    __shared__ bf16 As[128 * 64];
    __shared__ bf16 Bs[128 * 64];
    const int tid  = threadIdx.x;
    const int wave = tid >> 6, lane = tid & 63;
    const int quad = lane >> 4, l15 = lane & 15;
    const int m0 = blockIdx.x * 128, n0 = blockIdx.y * 128;
    const int wr = wave >> 1, wc = wave & 1;

    const int srow = wave * 8 + (lane >> 3);
    const int scol = ((lane & 7) ^ (lane >> 3)) * 8;
    char* ldsA0 = (char*)As + wave * 1024;
    char* ldsB0 = (char*)Bs + wave * 1024;
    const bf16* gA0 = A + (size_t)(m0 + srow) * K + scol;
    const bf16* gB0 = Bt + (size_t)(n0 + srow) * K + scol;

    const int sw = l15 & 7;

    f32x4 acc[4][4] = {};

    for (int kt = 0; kt < K; kt += 64) {
        __syncthreads();
#pragma unroll
        for (int c = 0; c < 4; c++)
            gl2lds16(gA0 + (size_t)c * 32 * K + kt, ldsA0 + c * 4096);
#pragma unroll
        for (int c = 0; c < 4; c++)
            gl2lds16(gB0 + (size_t)c * 32 * K + kt, ldsB0 + c * 4096);
        __syncthreads();

#pragma unroll
        for (int kg = 0; kg < 2; kg++) {
            bf16x8 af[4], bfr[4];
#pragma unroll
            for (int i = 0; i < 4; i++)
                af[i] = *(const bf16x8*)((const char*)As +
                         (wr * 64 + i * 16 + l15) * 128 + (((kg * 4 + quad) ^ sw) * 16));
#pragma unroll
            for (int i = 0; i < 4; i++)
                bfr[i] = *(const bf16x8*)((const char*)Bs +
                         (wc * 64 + i * 16 + l15) * 128 + (((kg * 4 + quad) ^ sw) * 16));
#pragma unroll
            for (int fr = 0; fr < 4; fr++)
#pragma unroll
                for (int fc = 0; fc < 4; fc++)
                    acc[fr][fc] = mfma_bf16(af[fr], bfr[fc], acc[fr][fc]);
        }
    }

#pragma unroll
    for (int fr = 0; fr < 4; fr++) {
        int row = m0 + wr * 64 + fr * 16 + quad * 4;
#pragma unroll
        for (int fc = 0; fc < 4; fc++) {
            int col = n0 + wc * 64 + fc * 16 + l15;
            float bv = bias[col];
#pragma unroll
            for (int r = 0; r < 4; r++)
                Cout[(size_t)(row + r) * N + col] = acc[fr][fc][r] + bv;
        }
    }
}

// ---------------------------------------------------------------- attention (r7, reverted best)
__global__ __launch_bounds__(256, 4) void attn(const bf16* __restrict__ Q,
                                               const bf16* __restrict__ K,
                                               const bf16* __restrict__ Vt,
                                               bf16* __restrict__ O) {
    __shared__ bf16 KsA[2][64 * 64];     // [buf][key][d]   XOR-swizzled slots
    __shared__ bf16 VsA[2][64 * 64];     // [buf][d][key]   XOR-swizzled slots

    const int tid  = threadIdx.x;
    const int wave = tid >> 6, lane = tid & 63;
    const int l31  = lane & 31, H = lane >> 5;
    const int bh = blockIdx.x, b = bh >> 4, h = bh & 15;
    const size_t rowbase = (size_t)b * SLEN;
    const int qb = blockIdx.y * 128 + wave * 32;
    const int hc = h * DHEAD;

    // Q fragments: B-operand of 32x32x16. lane holds Q[q=l31][d = ks*16 + H*8 + j]
    bf16x8 qf[4];
#pragma unroll
    for (int ks = 0; ks < 4; ks++)
        qf[ks] = *(const bf16x8*)(Q + (rowbase + qb + l31) * DEMBED
                                  + hc + ks * 16 + H * 8);

    f32x16 o[2] = {};
    float lsv = 0.0f;

    const bf16* Kbase = K + rowbase * DEMBED + hc;
    const bf16* Vbase = Vt + (size_t)bh * DHEAD * SLEN;

    // pre-swizzled global source so linear gl2lds dest yields XOR-swizzled LDS
    const int xcol = (((tid & 7) ^ ((tid >> 3) & 7)) * 8);
    const bf16* gK = Kbase + (size_t)(tid >> 3) * DEMBED + xcol;
    const bf16* gV = Vbase + (size_t)(tid >> 3) * SLEN + xcol;

    const int swz = l31 & 7;             // row XOR for reads

    // prologue: stage tile 0 into buffer 0
    {
        char* lk = (char*)KsA + wave * 1024;
        char* lv = (char*)VsA + wave * 1024;
        gl2lds16(gK, lk);
        gl2lds16(gK + (size_t)32 * DEMBED, lk + 32 * 128);
        gl2lds16(gV, lv);
        gl2lds16(gV + 32 * SLEN, lv + 32 * 128);
    }
    __syncthreads();

    int cur = 0;
    for (int kb = 0; kb < SLEN; kb += 64) {
        // prefetch next tile into the other buffer (no wait; drains at barrier)
        if (kb + 64 < SLEN) {
            char* lk = (char*)KsA + (cur ^ 1) * 8192 + wave * 1024;
            char* lv = (char*)VsA + (cur ^ 1) * 8192 + wave * 1024;
            gl2lds16(gK + (size_t)(kb + 64) * DEMBED, lk);
            gl2lds16(gK + (size_t)(kb + 96) * DEMBED, lk + 32 * 128);
            gl2lds16(gV + kb + 64, lv);
            gl2lds16(gV + 32 * SLEN + kb + 64, lv + 32 * 128);
        }

        const char* Kbuf = (const char*)KsA + cur * 8192;
        const char* Vbuf = (const char*)VsA + cur * 8192;

        // ---- QK^T (swapped): s = mfma(A=K, B=Q) -> S^T[key][q]
        f32x16 s0 = {}, s1 = {};
#pragma unroll
        for (int ks = 0; ks < 4; ks++) {
            bf16x8 kf0 = *(const bf16x8*)(Kbuf + l31 * 128
                          + (((2 * ks + H) ^ swz) * 16));
            bf16x8 kf1 = *(const bf16x8*)(Kbuf + (32 + l31) * 128
                          + (((2 * ks + H) ^ swz) * 16));
            s0 = mfma32(kf0, qf[ks], s0);
            s1 = mfma32(kf1, qf[ks], s1);
        }

        // ---- softmax (no max-sub; scale pre-folded into Q) + pack to bf16 pairs
        int c0[8], c1[8];
#pragma unroll
        for (int t = 0; t < 8; t++) {
            float a0 = __builtin_amdgcn_exp2f(s0[2 * t]);
            float a1 = __builtin_amdgcn_exp2f(s0[2 * t + 1]);
            float b0 = __builtin_amdgcn_exp2f(s1[2 * t]);
            float b1 = __builtin_amdgcn_exp2f(s1[2 * t + 1]);
            lsv += (a0 + a1) + (b0 + b1);
            union { bf16x2 h; int i; } p0, p1;
            p0.h[0] = (bf16)a0; p0.h[1] = (bf16)a1;
            p1.h[0] = (bf16)b0; p1.h[1] = (bf16)b1;
            c0[t] = p0.i;
            c1[t] = p1.i;
        }

        // ---- PV: o[dg] += mfma(A=P, B=V).  A-frag assembled in-register:
#pragma unroll
        for (int ks = 0; ks < 4; ks++) {
            const int* cc = (ks < 2) ? c0 : c1;
            const int ksl = ks & 1;
            auto w0 = __builtin_amdgcn_permlane32_swap(cc[4 * ksl + 0],
                                                       cc[4 * ksl + 2], false, false);
            auto w1 = __builtin_amdgcn_permlane32_swap(cc[4 * ksl + 1],
                                                       cc[4 * ksl + 3], false, false);
            union { int i[4]; bf16x8 v; } ap;
            ap.i[0] = w0[0]; ap.i[1] = w1[0]; ap.i[2] = w0[1]; ap.i[3] = w1[1];
#pragma unroll
            for (int dg = 0; dg < 2; dg++) {
                bf16x8 vf = *(const bf16x8*)(Vbuf + (dg * 32 + l31) * 128
                              + (((2 * ks + H) ^ swz) * 16));
                o[dg] = mfma32(ap.v, vf, o[dg]);
            }
        }

        __syncthreads();   // drains prefetch (vmcnt0) + protects buffer reuse
        cur ^= 1;
    }

    // ---- epilogue: softmax denominator + normalized store
    lsv += __shfl_xor(lsv, 32);
    float inv = 1.0f / lsv;      // valid for q = l31 in both halves
#pragma unroll
    for (int r = 0; r < 16; r++) {
        const int ql = (r & 3) + 8 * (r >> 2) + 4 * H;
        float iv = __shfl(inv, ql);
#pragma unroll
        for (int dg = 0; dg < 2; dg++)
            O[(rowbase + qb + ql) * DEMBED + hc + dg * 32 + l31] =
                (bf16)(o[dg][r] * iv);
    }
}

// ---------------------------------------------------------------- launch
extern "C" void kernel_launch(void* const* d_in, const int* in_sizes, int n_in,
                              void* d_out, int out_size, void* d_ws, size_t ws_size,
                              hipStream_t stream) {
    const float* x  = (const float*)d_in[0];
    const float* y  = (const float*)d_in[1];
    const float* Wq = (const float*)d_in[2];
    const float* bq = (const float*)d_in[3];
    const float* Wk = (const float*)d_in[4];
    const float* bk = (const float*)d_in[5];
    const float* Wv = (const float*)d_in[6];
    const float* bv = (const float*)d_in[7];
    const float* Wo = (const float*)d_in[8];
    const float* bo = (const float*)d_in[9];
    float* out = (float*)d_out;

    char* ws = (char*)d_ws;
    size_t off = 0;
    auto alloc = [&](size_t bytes) {
        void* p = ws + off;
        off += (bytes + 255) & ~(size_t)255;
        return p;
    };
    bf16* xb  = (bf16*)alloc((size_t)MROWS * DEMBED * 2);
    bf16* yb  = (bf16*)alloc((size_t)MROWS * DCROSS * 2);
    bf16* Wqt = (bf16*)alloc((size_t)DEMBED * DEMBED * 2);
    bf16* Wkt = (bf16*)alloc((size_t)DEMBED * DCROSS * 2);
    bf16* Wvt = (bf16*)alloc((size_t)DEMBED * DCROSS * 2);
    bf16* Wot = (bf16*)alloc((size_t)DEMBED * DEMBED * 2);
    bf16* Qb  = (bf16*)alloc((size_t)MROWS * DEMBED * 2);
    bf16* Kb  = (bf16*)alloc((size_t)MROWS * DEMBED * 2);
    bf16* Vtb = (bf16*)alloc((size_t)MROWS * DEMBED * 2);  // V^T per head
    bf16* Ab  = (bf16*)alloc((size_t)MROWS * DEMBED * 2);
    if (off > ws_size) return;

    {
        PrepArgs a;
        a.wsrc[0] = Wq; a.wdst[0] = Wqt; a.wK[0] = DEMBED;
        a.wsrc[1] = Wk; a.wdst[1] = Wkt; a.wK[1] = DCROSS;
        a.wsrc[2] = Wv; a.wdst[2] = Wvt; a.wK[2] = DCROSS;
        a.wsrc[3] = Wo; a.wdst[3] = Wot; a.wK[3] = DEMBED;
        a.x = x; a.y = y; a.xb = xb; a.yb = yb;
        int ncvt = (MROWS * DEMBED / 4 + MROWS * DCROSS / 4 + 255) / 256;
        prep_all<<<NTRB + ncvt, 256, 0, stream>>>(a);
    }

    {
        QkvArgs a;
        a.xb = xb; a.yb = yb; a.Wqt = Wqt; a.Wkt = Wkt; a.Wvt = Wvt;
        a.bq = bq; a.bk = bk; a.bv = bv;
        a.Qb = Qb; a.Kb = Kb; a.Vt = Vtb;
        a.qscale = 0.125f * 1.4426950408889634f;   // 1/sqrt(64) * log2(e)
        gemm_qkv<<<768, 512, 0, stream>>>(a);
    }

    attn<<<dim3(BATCH * NHEADS, SLEN / 128), 256, 0, stream>>>(Qb, Kb, Vtb, Ab);

    gemm_o<<<dim3(MROWS / 128, DEMBED / 128), 256, 0, stream>>>(Ab, Wot, bo, out);
}

// Round 7
// 287.708 us; speedup vs baseline: 1.0481x; 1.0374x over previous
//
#include <hip/hip_runtime.h>

#define NHEADS 16
#define DEMBED 1024
#define DCROSS 768
#define DHEAD  64
#define BATCH  4
#define SLEN   2048
#define MROWS  (BATCH * SLEN)   // 8192

using bf16   = __bf16;
using bf16x8 = __attribute__((ext_vector_type(8))) __bf16;
using bf16x4 = __attribute__((ext_vector_type(4))) __bf16;
using bf16x2 = __attribute__((ext_vector_type(2))) __bf16;
using f32x4  = __attribute__((ext_vector_type(4))) float;
using f32x16 = __attribute__((ext_vector_type(16))) float;

__device__ __forceinline__ f32x4 mfma_bf16(bf16x8 a, bf16x8 b, f32x4 c) {
    return __builtin_amdgcn_mfma_f32_16x16x32_bf16(a, b, c, 0, 0, 0);
}
__device__ __forceinline__ f32x16 mfma32(bf16x8 a, bf16x8 b, f32x16 c) {
    return __builtin_amdgcn_mfma_f32_32x32x16_bf16(a, b, c, 0, 0, 0);
}

// async global->LDS, 16B per lane; lds dest = wave-uniform base + lane*16
__device__ __forceinline__ void gl2lds16(const void* g, void* l) {
    __builtin_amdgcn_global_load_lds(
        (const __attribute__((address_space(1))) void*)g,
        (__attribute__((address_space(3))) void*)l, 16, 0, 0);
}

// ---------------------------------------------------------------- prep (one kernel)
struct PrepArgs {
    const float* wsrc[4]; bf16* wdst[4]; int wK[4];
    const float *x, *y; bf16 *xb, *yb;
};
#define NTRB 4096
__global__ void prep_all(PrepArgs a) {
    const int bid = blockIdx.x;
    const int tid = threadIdx.x;
    if (bid < NTRB) {
        __shared__ float tile[32][33];
        const int which = bid >> 10, rem = bid & 1023;
        const int K = a.wK[which], N = DEMBED;
        const int n0 = (rem & 31) * 32, k0 = (rem >> 5) * 32;
        if (k0 >= K) return;
        const float* W = a.wsrc[which];
        bf16* Wt = a.wdst[which];
        const int tx = tid & 31, ty = tid >> 5;
#pragma unroll
        for (int i = 0; i < 32; i += 8)
            tile[ty + i][tx] = W[(size_t)(k0 + ty + i) * N + n0 + tx];
        __syncthreads();
#pragma unroll
        for (int i = 0; i < 32; i += 8)
            Wt[(size_t)(n0 + ty + i) * K + k0 + tx] = (bf16)tile[tx][ty + i];
    } else {
        const int n4x = MROWS * DEMBED / 4;
        const int n4y = MROWS * DCROSS / 4;
        int i = (bid - NTRB) * 256 + tid;
        const float* src; bf16* dst; int j;
        if (i < n4x) { src = a.x; dst = a.xb; j = i; }
        else { j = i - n4x; if (j >= n4y) return; src = a.y; dst = a.yb; }
        float4 v = ((const float4*)src)[j];
        bf16x4 o = { (bf16)v.x, (bf16)v.y, (bf16)v.z, (bf16)v.w };
        ((bf16x4*)dst)[j] = o;
    }
}

// ---------------------------------------------------------------- fused QKV GEMM (r6 + T1 XCD swizzle)
// BK=64: 128x128 tile, 256 thr, 16B async staging, XOR-swizzled LDS.
// XCD-chunked blockIdx swizzle (1536 % 8 == 0): each XCD gets a contiguous
// 192-block chunk of tile space -> A-panel re-reads (8 N-blocks share one
// M-panel) hit the same XCD's L2 instead of being scattered across 8 L2s.
struct QkvArgs {
    const bf16 *xb, *yb, *Wqt, *Wkt, *Wvt;
    const float *bq, *bk, *bv;
    bf16 *Qb, *Kb, *Vt;
    float qscale;
};
__global__ __launch_bounds__(256, 3) void gemm_qkv(QkvArgs a) {
    __shared__ bf16 As[128 * 64];
    __shared__ bf16 Bs[128 * 64];
    const int rb = blockIdx.x;
    const int id = (rb & 7) * 192 + (rb >> 3);   // T1 bijective XCD swizzle
    const int cls = id >> 9;   // 0=Q 1=K 2=V
    const bf16 *A, *Bt;
    const float* bias;
    int K, m0, n0;
    if (cls == 0) { int t = id;        m0 = (t >> 3) * 128; n0 = (t & 7) * 128;
                    A = a.xb;  Bt = a.Wqt; bias = a.bq; K = DEMBED; }
    else if (cls == 1) { int t = id - 512;  m0 = (t >> 3) * 128; n0 = (t & 7) * 128;
                    A = a.yb;  Bt = a.Wkt; bias = a.bk; K = DCROSS; }
    else { int t = id - 1024; m0 = (t >> 6) * 128; n0 = (t & 63) * 128;
                    A = a.Wvt; Bt = a.yb;  bias = a.bv; K = DCROSS; }

    const int tid  = threadIdx.x;
    const int wave = tid >> 6, lane = tid & 63;
    const int quad = lane >> 4, l15 = lane & 15;
    const int wr = wave >> 1, wc = wave & 1;

    const int srow = wave * 8 + (lane >> 3);
    const int scol = ((lane & 7) ^ (lane >> 3)) * 8;
    char* ldsA0 = (char*)As + wave * 1024;
    char* ldsB0 = (char*)Bs + wave * 1024;
    const bf16* gA0 = A + (size_t)(m0 + srow) * K + scol;
    const bf16* gB0 = Bt + (size_t)(n0 + srow) * K + scol;

    const int sw = l15 & 7;

    f32x4 acc[4][4] = {};

    for (int kt = 0; kt < K; kt += 64) {
        __syncthreads();
#pragma unroll
        for (int c = 0; c < 4; c++)
            gl2lds16(gA0 + (size_t)c * 32 * K + kt, ldsA0 + c * 4096);
#pragma unroll
        for (int c = 0; c < 4; c++)
            gl2lds16(gB0 + (size_t)c * 32 * K + kt, ldsB0 + c * 4096);
        __syncthreads();

#pragma unroll
        for (int kg = 0; kg < 2; kg++) {
            bf16x8 af[4], bfr[4];
#pragma unroll
            for (int i = 0; i < 4; i++)
                af[i] = *(const bf16x8*)((const char*)As +
                         (wr * 64 + i * 16 + l15) * 128 + (((kg * 4 + quad) ^ sw) * 16));
#pragma unroll
            for (int i = 0; i < 4; i++)
                bfr[i] = *(const bf16x8*)((const char*)Bs +
                         (wc * 64 + i * 16 + l15) * 128 + (((kg * 4 + quad) ^ sw) * 16));
#pragma unroll
            for (int fr = 0; fr < 4; fr++)
#pragma unroll
                for (int fc = 0; fc < 4; fc++)
                    acc[fr][fc] = mfma_bf16(af[fr], bfr[fc], acc[fr][fc]);
        }
    }

    if (cls < 2) {
        bf16* Cout = (cls == 0) ? a.Qb : a.Kb;
        const float alpha = (cls == 0) ? a.qscale : 1.0f;
#pragma unroll
        for (int fr = 0; fr < 4; fr++) {
            int row = m0 + wr * 64 + fr * 16 + quad * 4;
#pragma unroll
            for (int fc = 0; fc < 4; fc++) {
                int col = n0 + wc * 64 + fc * 16 + l15;
                float bv = bias[col];
#pragma unroll
                for (int r = 0; r < 4; r++)
                    Cout[(size_t)(row + r) * DEMBED + col] =
                        (bf16)((acc[fr][fc][r] + bv) * alpha);
            }
        }
    } else {
        const int b = n0 >> 11;
        const size_t bbase = (size_t)b * DEMBED * SLEN;
#pragma unroll
        for (int fr = 0; fr < 4; fr++) {
            int row = m0 + wr * 64 + fr * 16 + quad * 4;
#pragma unroll
            for (int fc = 0; fc < 4; fc++) {
                int col = n0 + wc * 64 + fc * 16 + l15;
                int s = col & (SLEN - 1);
#pragma unroll
                for (int r = 0; r < 4; r++)
                    a.Vt[bbase + (size_t)(row + r) * SLEN + s] =
                        (bf16)(acc[fr][fc][r] + bias[row + r]);
            }
        }
    }
}

// ---------------------------------------------------------------- O GEMM (r6 128^2 + T1 XCD swizzle)
// 1D grid 512 blocks; XCD-chunked swizzle (512 % 8 == 0, chunks of 64).
__global__ __launch_bounds__(256, 3) void gemm_o(const bf16* __restrict__ A,
                                                 const bf16* __restrict__ Bt,
                                                 const float* __restrict__ bias,
                                                 float* __restrict__ Cout) {
    const int K = DEMBED, N = DEMBED;
    __shared__ bf16 As[128 * 64];
    __shared__ bf16 Bs[128 * 64];
    const int tid  = threadIdx.x;
    const int wave = tid >> 6, lane = tid & 63;
    const int quad = lane >> 4, l15 = lane & 15;
    const int rb = blockIdx.x;
    const int bid = (rb & 7) * 64 + (rb >> 3);   // T1 bijective XCD swizzle
    const int m0 = (bid >> 3) * 128, n0 = (bid & 7) * 128;
    const int wr = wave >> 1, wc = wave & 1;

    const int srow = wave * 8 + (lane >> 3);
    const int scol = ((lane & 7) ^ (lane >> 3)) * 8;
    char* ldsA0 = (char*)As + wave * 1024;
    char* ldsB0 = (char*)Bs + wave * 1024;
    const bf16* gA0 = A + (size_t)(m0 + srow) * K + scol;
    const bf16* gB0 = Bt + (size_t)(n0 + srow) * K + scol;

    const int sw = l15 & 7;

    f32x4 acc[4][4] = {};

    for (int kt = 0; kt < K; kt += 64) {
        __syncthreads();
#pragma unroll
        for (int c = 0; c < 4; c++)
            gl2lds16(gA0 + (size_t)c * 32 * K + kt, ldsA0 + c * 4096);
#pragma unroll
        for (int c = 0; c < 4; c++)
            gl2lds16(gB0 + (size_t)c * 32 * K + kt, ldsB0 + c * 4096);
        __syncthreads();

#pragma unroll
        for (int kg = 0; kg < 2; kg++) {
            bf16x8 af[4], bfr[4];
#pragma unroll
            for (int i = 0; i < 4; i++)
                af[i] = *(const bf16x8*)((const char*)As +
                         (wr * 64 + i * 16 + l15) * 128 + (((kg * 4 + quad) ^ sw) * 16));
#pragma unroll
            for (int i = 0; i < 4; i++)
                bfr[i] = *(const bf16x8*)((const char*)Bs +
                         (wc * 64 + i * 16 + l15) * 128 + (((kg * 4 + quad) ^ sw) * 16));
#pragma unroll
            for (int fr = 0; fr < 4; fr++)
#pragma unroll
                for (int fc = 0; fc < 4; fc++)
                    acc[fr][fc] = mfma_bf16(af[fr], bfr[fc], acc[fr][fc]);
        }
    }

#pragma unroll
    for (int fr = 0; fr < 4; fr++) {
        int row = m0 + wr * 64 + fr * 16 + quad * 4;
#pragma unroll
        for (int fc = 0; fc < 4; fc++) {
            int col = n0 + wc * 64 + fc * 16 + l15;
            float bv = bias[col];
#pragma unroll
            for (int r = 0; r < 4; r++)
                Cout[(size_t)(row + r) * N + col] = acc[fr][fc][r] + bv;
        }
    }
}

// ---------------------------------------------------------------- attention (r7, best measured)
__global__ __launch_bounds__(256, 4) void attn(const bf16* __restrict__ Q,
                                               const bf16* __restrict__ K,
                                               const bf16* __restrict__ Vt,
                                               bf16* __restrict__ O) {
    __shared__ bf16 KsA[2][64 * 64];     // [buf][key][d]   XOR-swizzled slots
    __shared__ bf16 VsA[2][64 * 64];     // [buf][d][key]   XOR-swizzled slots

    const int tid  = threadIdx.x;
    const int wave = tid >> 6, lane = tid & 63;
    const int l31  = lane & 31, H = lane >> 5;
    const int bh = blockIdx.x, b = bh >> 4, h = bh & 15;
    const size_t rowbase = (size_t)b * SLEN;
    const int qb = blockIdx.y * 128 + wave * 32;
    const int hc = h * DHEAD;

    // Q fragments: B-operand of 32x32x16. lane holds Q[q=l31][d = ks*16 + H*8 + j]
    bf16x8 qf[4];
#pragma unroll
    for (int ks = 0; ks < 4; ks++)
        qf[ks] = *(const bf16x8*)(Q + (rowbase + qb + l31) * DEMBED
                                  + hc + ks * 16 + H * 8);

    f32x16 o[2] = {};
    float lsv = 0.0f;

    const bf16* Kbase = K + rowbase * DEMBED + hc;
    const bf16* Vbase = Vt + (size_t)bh * DHEAD * SLEN;

    // pre-swizzled global source so linear gl2lds dest yields XOR-swizzled LDS
    const int xcol = (((tid & 7) ^ ((tid >> 3) & 7)) * 8);
    const bf16* gK = Kbase + (size_t)(tid >> 3) * DEMBED + xcol;
    const bf16* gV = Vbase + (size_t)(tid >> 3) * SLEN + xcol;

    const int swz = l31 & 7;             // row XOR for reads

    // prologue: stage tile 0 into buffer 0
    {
        char* lk = (char*)KsA + wave * 1024;
        char* lv = (char*)VsA + wave * 1024;
        gl2lds16(gK, lk);
        gl2lds16(gK + (size_t)32 * DEMBED, lk + 32 * 128);
        gl2lds16(gV, lv);
        gl2lds16(gV + 32 * SLEN, lv + 32 * 128);
    }
    __syncthreads();

    int cur = 0;
    for (int kb = 0; kb < SLEN; kb += 64) {
        // prefetch next tile into the other buffer (no wait; drains at barrier)
        if (kb + 64 < SLEN) {
            char* lk = (char*)KsA + (cur ^ 1) * 8192 + wave * 1024;
            char* lv = (char*)VsA + (cur ^ 1) * 8192 + wave * 1024;
            gl2lds16(gK + (size_t)(kb + 64) * DEMBED, lk);
            gl2lds16(gK + (size_t)(kb + 96) * DEMBED, lk + 32 * 128);
            gl2lds16(gV + kb + 64, lv);
            gl2lds16(gV + 32 * SLEN + kb + 64, lv + 32 * 128);
        }

        const char* Kbuf = (const char*)KsA + cur * 8192;
        const char* Vbuf = (const char*)VsA + cur * 8192;

        // ---- QK^T (swapped): s = mfma(A=K, B=Q) -> S^T[key][q]
        f32x16 s0 = {}, s1 = {};
#pragma unroll
        for (int ks = 0; ks < 4; ks++) {
            bf16x8 kf0 = *(const bf16x8*)(Kbuf + l31 * 128
                          + (((2 * ks + H) ^ swz) * 16));
            bf16x8 kf1 = *(const bf16x8*)(Kbuf + (32 + l31) * 128
                          + (((2 * ks + H) ^ swz) * 16));
            s0 = mfma32(kf0, qf[ks], s0);
            s1 = mfma32(kf1, qf[ks], s1);
        }

        // ---- softmax (no max-sub; scale pre-folded into Q) + pack to bf16 pairs
        int c0[8], c1[8];
#pragma unroll
        for (int t = 0; t < 8; t++) {
            float a0 = __builtin_amdgcn_exp2f(s0[2 * t]);
            float a1 = __builtin_amdgcn_exp2f(s0[2 * t + 1]);
            float b0 = __builtin_amdgcn_exp2f(s1[2 * t]);
            float b1 = __builtin_amdgcn_exp2f(s1[2 * t + 1]);
            lsv += (a0 + a1) + (b0 + b1);
            union { bf16x2 h; int i; } p0, p1;
            p0.h[0] = (bf16)a0; p0.h[1] = (bf16)a1;
            p1.h[0] = (bf16)b0; p1.h[1] = (bf16)b1;
            c0[t] = p0.i;
            c1[t] = p1.i;
        }

        // ---- PV: o[dg] += mfma(A=P, B=V).  A-frag assembled in-register:
#pragma unroll
        for (int ks = 0; ks < 4; ks++) {
            const int* cc = (ks < 2) ? c0 : c1;
            const int ksl = ks & 1;
            auto w0 = __builtin_amdgcn_permlane32_swap(cc[4 * ksl + 0],
                                                       cc[4 * ksl + 2], false, false);
            auto w1 = __builtin_amdgcn_permlane32_swap(cc[4 * ksl + 1],
                                                       cc[4 * ksl + 3], false, false);
            union { int i[4]; bf16x8 v; } ap;
            ap.i[0] = w0[0]; ap.i[1] = w1[0]; ap.i[2] = w0[1]; ap.i[3] = w1[1];
#pragma unroll
            for (int dg = 0; dg < 2; dg++) {
                bf16x8 vf = *(const bf16x8*)(Vbuf + (dg * 32 + l31) * 128
                              + (((2 * ks + H) ^ swz) * 16));
                o[dg] = mfma32(ap.v, vf, o[dg]);
            }
        }

        __syncthreads();   // drains prefetch (vmcnt0) + protects buffer reuse
        cur ^= 1;
    }

    // ---- epilogue: softmax denominator + normalized store
    lsv += __shfl_xor(lsv, 32);
    float inv = 1.0f / lsv;      // valid for q = l31 in both halves
#pragma unroll
    for (int r = 0; r < 16; r++) {
        const int ql = (r & 3) + 8 * (r >> 2) + 4 * H;
        float iv = __shfl(inv, ql);
#pragma unroll
        for (int dg = 0; dg < 2; dg++)
            O[(rowbase + qb + ql) * DEMBED + hc + dg * 32 + l31] =
                (bf16)(o[dg][r] * iv);
    }
}

// ---------------------------------------------------------------- launch
extern "C" void kernel_launch(void* const* d_in, const int* in_sizes, int n_in,
                              void* d_out, int out_size, void* d_ws, size_t ws_size,
                              hipStream_t stream) {
    const float* x  = (const float*)d_in[0];
    const float* y  = (const float*)d_in[1];
    const float* Wq = (const float*)d_in[2];
    const float* bq = (const float*)d_in[3];
    const float* Wk = (const float*)d_in[4];
    const float* bk = (const float*)d_in[5];
    const float* Wv = (const float*)d_in[6];
    const float* bv = (const float*)d_in[7];
    const float* Wo = (const float*)d_in[8];
    const float* bo = (const float*)d_in[9];
    float* out = (float*)d_out;

    char* ws = (char*)d_ws;
    size_t off = 0;
    auto alloc = [&](size_t bytes) {
        void* p = ws + off;
        off += (bytes + 255) & ~(size_t)255;
        return p;
    };
    bf16* xb  = (bf16*)alloc((size_t)MROWS * DEMBED * 2);
    bf16* yb  = (bf16*)alloc((size_t)MROWS * DCROSS * 2);
    bf16* Wqt = (bf16*)alloc((size_t)DEMBED * DEMBED * 2);
    bf16* Wkt = (bf16*)alloc((size_t)DEMBED * DCROSS * 2);
    bf16* Wvt = (bf16*)alloc((size_t)DEMBED * DCROSS * 2);
    bf16* Wot = (bf16*)alloc((size_t)DEMBED * DEMBED * 2);
    bf16* Qb  = (bf16*)alloc((size_t)MROWS * DEMBED * 2);
    bf16* Kb  = (bf16*)alloc((size_t)MROWS * DEMBED * 2);
    bf16* Vtb = (bf16*)alloc((size_t)MROWS * DEMBED * 2);  // V^T per head
    bf16* Ab  = (bf16*)alloc((size_t)MROWS * DEMBED * 2);
    if (off > ws_size) return;

    {
        PrepArgs a;
        a.wsrc[0] = Wq; a.wdst[0] = Wqt; a.wK[0] = DEMBED;
        a.wsrc[1] = Wk; a.wdst[1] = Wkt; a.wK[1] = DCROSS;
        a.wsrc[2] = Wv; a.wdst[2] = Wvt; a.wK[2] = DCROSS;
        a.wsrc[3] = Wo; a.wdst[3] = Wot; a.wK[3] = DEMBED;
        a.x = x; a.y = y; a.xb = xb; a.yb = yb;
        int ncvt = (MROWS * DEMBED / 4 + MROWS * DCROSS / 4 + 255) / 256;
        prep_all<<<NTRB + ncvt, 256, 0, stream>>>(a);
    }

    {
        QkvArgs a;
        a.xb = xb; a.yb = yb; a.Wqt = Wqt; a.Wkt = Wkt; a.Wvt = Wvt;
        a.bq = bq; a.bk = bk; a.bv = bv;
        a.Qb = Qb; a.Kb = Kb; a.Vt = Vtb;
        a.qscale = 0.125f * 1.4426950408889634f;   // 1/sqrt(64) * log2(e)
        gemm_qkv<<<1536, 256, 0, stream>>>(a);
    }

    attn<<<dim3(BATCH * NHEADS, SLEN / 128), 256, 0, stream>>>(Qb, Kb, Vtb, Ab);

    gemm_o<<<512, 256, 0, stream>>>(Ab, Wot, bo, out);
}

// Round 8
// 282.575 us; speedup vs baseline: 1.0671x; 1.0182x over previous
//
#include <hip/hip_runtime.h>

#define NHEADS 16
#define DEMBED 1024
#define DCROSS 768
#define DHEAD  64
#define BATCH  4
#define SLEN   2048
#define MROWS  (BATCH * SLEN)   // 8192

using bf16   = __bf16;
using bf16x8 = __attribute__((ext_vector_type(8))) __bf16;
using bf16x4 = __attribute__((ext_vector_type(4))) __bf16;
using bf16x2 = __attribute__((ext_vector_type(2))) __bf16;
using f32x4  = __attribute__((ext_vector_type(4))) float;
using f32x16 = __attribute__((ext_vector_type(16))) float;

__device__ __forceinline__ f32x4 mfma_bf16(bf16x8 a, bf16x8 b, f32x4 c) {
    return __builtin_amdgcn_mfma_f32_16x16x32_bf16(a, b, c, 0, 0, 0);
}
__device__ __forceinline__ f32x16 mfma32(bf16x8 a, bf16x8 b, f32x16 c) {
    return __builtin_amdgcn_mfma_f32_32x32x16_bf16(a, b, c, 0, 0, 0);
}

// async global->LDS, 16B per lane; lds dest = wave-uniform base + lane*16
__device__ __forceinline__ void gl2lds16(const void* g, void* l) {
    __builtin_amdgcn_global_load_lds(
        (const __attribute__((address_space(1))) void*)g,
        (__attribute__((address_space(3))) void*)l, 16, 0, 0);
}

// ---------------------------------------------------------------- prep (one kernel)
struct PrepArgs {
    const float* wsrc[4]; bf16* wdst[4]; int wK[4];
    const float *x, *y; bf16 *xb, *yb;
};
#define NTRB 4096
__global__ void prep_all(PrepArgs a) {
    const int bid = blockIdx.x;
    const int tid = threadIdx.x;
    if (bid < NTRB) {
        __shared__ float tile[32][33];
        const int which = bid >> 10, rem = bid & 1023;
        const int K = a.wK[which], N = DEMBED;
        const int n0 = (rem & 31) * 32, k0 = (rem >> 5) * 32;
        if (k0 >= K) return;
        const float* W = a.wsrc[which];
        bf16* Wt = a.wdst[which];
        const int tx = tid & 31, ty = tid >> 5;
#pragma unroll
        for (int i = 0; i < 32; i += 8)
            tile[ty + i][tx] = W[(size_t)(k0 + ty + i) * N + n0 + tx];
        __syncthreads();
#pragma unroll
        for (int i = 0; i < 32; i += 8)
            Wt[(size_t)(n0 + ty + i) * K + k0 + tx] = (bf16)tile[tx][ty + i];
    } else {
        const int n4x = MROWS * DEMBED / 4;
        const int n4y = MROWS * DCROSS / 4;
        int i = (bid - NTRB) * 256 + tid;
        const float* src; bf16* dst; int j;
        if (i < n4x) { src = a.x; dst = a.xb; j = i; }
        else { j = i - n4x; if (j >= n4y) return; src = a.y; dst = a.yb; }
        float4 v = ((const float4*)src)[j];
        bf16x4 o = { (bf16)v.x, (bf16)v.y, (bf16)v.z, (bf16)v.w };
        ((bf16x4*)dst)[j] = o;
    }
}

// ---------------------------------------------------------------- fused QKV GEMM (r6, no swizzle)
struct QkvArgs {
    const bf16 *xb, *yb, *Wqt, *Wkt, *Wvt;
    const float *bq, *bk, *bv;
    bf16 *Qb, *Kb, *Vt;
    float qscale;
};
__global__ __launch_bounds__(256, 3) void gemm_qkv(QkvArgs a) {
    __shared__ bf16 As[128 * 64];
    __shared__ bf16 Bs[128 * 64];
    const int id = blockIdx.x;
    const int cls = id >> 9;   // 0=Q 1=K 2=V
    const bf16 *A, *Bt;
    const float* bias;
    int K, m0, n0;
    if (cls == 0) { int t = id;        m0 = (t >> 3) * 128; n0 = (t & 7) * 128;
                    A = a.xb;  Bt = a.Wqt; bias = a.bq; K = DEMBED; }
    else if (cls == 1) { int t = id - 512;  m0 = (t >> 3) * 128; n0 = (t & 7) * 128;
                    A = a.yb;  Bt = a.Wkt; bias = a.bk; K = DCROSS; }
    else { int t = id - 1024; m0 = (t >> 6) * 128; n0 = (t & 63) * 128;
                    A = a.Wvt; Bt = a.yb;  bias = a.bv; K = DCROSS; }

    const int tid  = threadIdx.x;
    const int wave = tid >> 6, lane = tid & 63;
    const int quad = lane >> 4, l15 = lane & 15;
    const int wr = wave >> 1, wc = wave & 1;

    const int srow = wave * 8 + (lane >> 3);
    const int scol = ((lane & 7) ^ (lane >> 3)) * 8;
    char* ldsA0 = (char*)As + wave * 1024;
    char* ldsB0 = (char*)Bs + wave * 1024;
    const bf16* gA0 = A + (size_t)(m0 + srow) * K + scol;
    const bf16* gB0 = Bt + (size_t)(n0 + srow) * K + scol;

    const int sw = l15 & 7;

    f32x4 acc[4][4] = {};

    for (int kt = 0; kt < K; kt += 64) {
        __syncthreads();
#pragma unroll
        for (int c = 0; c < 4; c++)
            gl2lds16(gA0 + (size_t)c * 32 * K + kt, ldsA0 + c * 4096);
#pragma unroll
        for (int c = 0; c < 4; c++)
            gl2lds16(gB0 + (size_t)c * 32 * K + kt, ldsB0 + c * 4096);
        __syncthreads();

#pragma unroll
        for (int kg = 0; kg < 2; kg++) {
            bf16x8 af[4], bfr[4];
#pragma unroll
            for (int i = 0; i < 4; i++)
                af[i] = *(const bf16x8*)((const char*)As +
                         (wr * 64 + i * 16 + l15) * 128 + (((kg * 4 + quad) ^ sw) * 16));
#pragma unroll
            for (int i = 0; i < 4; i++)
                bfr[i] = *(const bf16x8*)((const char*)Bs +
                         (wc * 64 + i * 16 + l15) * 128 + (((kg * 4 + quad) ^ sw) * 16));
#pragma unroll
            for (int fr = 0; fr < 4; fr++)
#pragma unroll
                for (int fc = 0; fc < 4; fc++)
                    acc[fr][fc] = mfma_bf16(af[fr], bfr[fc], acc[fr][fc]);
        }
    }

    if (cls < 2) {
        bf16* Cout = (cls == 0) ? a.Qb : a.Kb;
        const float alpha = (cls == 0) ? a.qscale : 1.0f;
#pragma unroll
        for (int fr = 0; fr < 4; fr++) {
            int row = m0 + wr * 64 + fr * 16 + quad * 4;
#pragma unroll
            for (int fc = 0; fc < 4; fc++) {
                int col = n0 + wc * 64 + fc * 16 + l15;
                float bv = bias[col];
#pragma unroll
                for (int r = 0; r < 4; r++)
                    Cout[(size_t)(row + r) * DEMBED + col] =
                        (bf16)((acc[fr][fc][r] + bv) * alpha);
            }
        }
    } else {
        const int b = n0 >> 11;
        const size_t bbase = (size_t)b * DEMBED * SLEN;
#pragma unroll
        for (int fr = 0; fr < 4; fr++) {
            int row = m0 + wr * 64 + fr * 16 + quad * 4;
#pragma unroll
            for (int fc = 0; fc < 4; fc++) {
                int col = n0 + wc * 64 + fc * 16 + l15;
                int s = col & (SLEN - 1);
#pragma unroll
                for (int r = 0; r < 4; r++)
                    a.Vt[bbase + (size_t)(row + r) * SLEN + s] =
                        (bf16)(acc[fr][fc][r] + bias[row + r]);
            }
        }
    }
}

// ---------------------------------------------------------------- O GEMM (r6 128^2, no swizzle)
__global__ __launch_bounds__(256, 3) void gemm_o(const bf16* __restrict__ A,
                                                 const bf16* __restrict__ Bt,
                                                 const float* __restrict__ bias,
                                                 float* __restrict__ Cout) {
    const int K = DEMBED, N = DEMBED;
    __shared__ bf16 As[128 * 64];
    __shared__ bf16 Bs[128 * 64];
    const int tid  = threadIdx.x;
    const int wave = tid >> 6, lane = tid & 63;
    const int quad = lane >> 4, l15 = lane & 15;
    const int m0 = blockIdx.x * 128, n0 = blockIdx.y * 128;
    const int wr = wave >> 1, wc = wave & 1;

    const int srow = wave * 8 + (lane >> 3);
    const int scol = ((lane & 7) ^ (lane >> 3)) * 8;
    char* ldsA0 = (char*)As + wave * 1024;
    char* ldsB0 = (char*)Bs + wave * 1024;
    const bf16* gA0 = A + (size_t)(m0 + srow) * K + scol;
    const bf16* gB0 = Bt + (size_t)(n0 + srow) * K + scol;

    const int sw = l15 & 7;

    f32x4 acc[4][4] = {};

    for (int kt = 0; kt < K; kt += 64) {
        __syncthreads();
#pragma unroll
        for (int c = 0; c < 4; c++)
            gl2lds16(gA0 + (size_t)c * 32 * K + kt, ldsA0 + c * 4096);
#pragma unroll
        for (int c = 0; c < 4; c++)
            gl2lds16(gB0 + (size_t)c * 32 * K + kt, ldsB0 + c * 4096);
        __syncthreads();

#pragma unroll
        for (int kg = 0; kg < 2; kg++) {
            bf16x8 af[4], bfr[4];
#pragma unroll
            for (int i = 0; i < 4; i++)
                af[i] = *(const bf16x8*)((const char*)As +
                         (wr * 64 + i * 16 + l15) * 128 + (((kg * 4 + quad) ^ sw) * 16));
#pragma unroll
            for (int i = 0; i < 4; i++)
                bfr[i] = *(const bf16x8*)((const char*)Bs +
                         (wc * 64 + i * 16 + l15) * 128 + (((kg * 4 + quad) ^ sw) * 16));
#pragma unroll
            for (int fr = 0; fr < 4; fr++)
#pragma unroll
                for (int fc = 0; fc < 4; fc++)
                    acc[fr][fc] = mfma_bf16(af[fr], bfr[fc], acc[fr][fc]);
        }
    }

#pragma unroll
    for (int fr = 0; fr < 4; fr++) {
        int row = m0 + wr * 64 + fr * 16 + quad * 4;
#pragma unroll
        for (int fc = 0; fc < 4; fc++) {
            int col = n0 + wc * 64 + fc * 16 + l15;
            float bv = bias[col];
#pragma unroll
            for (int r = 0; r < 4; r++)
                Cout[(size_t)(row + r) * N + col] = acc[fr][fc][r] + bv;
        }
    }
}

// ---------------------------------------------------------------- attention (r14)
// r7 structure + per-block STAGGERED K-tile iteration order: softmax/PV are
// order-independent reductions over keys, so each block walks the 32 K-tiles
// circularly starting at a per-block offset. Breaks the cross-block phase
// convoy (all blocks doing MFMA / VALU simultaneously -> pipes alternate
// instead of overlap); K/V are L3-resident so reduced temporal sharing is
// absorbed by L3.
__global__ __launch_bounds__(256, 4) void attn(const bf16* __restrict__ Q,
                                               const bf16* __restrict__ K,
                                               const bf16* __restrict__ Vt,
                                               bf16* __restrict__ O) {
    __shared__ bf16 KsA[2][64 * 64];     // [buf][key][d]   XOR-swizzled slots
    __shared__ bf16 VsA[2][64 * 64];     // [buf][d][key]   XOR-swizzled slots

    const int tid  = threadIdx.x;
    const int wave = tid >> 6, lane = tid & 63;
    const int l31  = lane & 31, H = lane >> 5;
    const int bh = blockIdx.x, b = bh >> 4, h = bh & 15;
    const size_t rowbase = (size_t)b * SLEN;
    const int qb = blockIdx.y * 128 + wave * 32;
    const int hc = h * DHEAD;

    // Q fragments: B-operand of 32x32x16. lane holds Q[q=l31][d = ks*16 + H*8 + j]
    bf16x8 qf[4];
#pragma unroll
    for (int ks = 0; ks < 4; ks++)
        qf[ks] = *(const bf16x8*)(Q + (rowbase + qb + l31) * DEMBED
                                  + hc + ks * 16 + H * 8);

    f32x16 o[2] = {};
    float lsv = 0.0f;

    const bf16* Kbase = K + rowbase * DEMBED + hc;
    const bf16* Vbase = Vt + (size_t)bh * DHEAD * SLEN;

    // pre-swizzled global source so linear gl2lds dest yields XOR-swizzled LDS
    const int xcol = (((tid & 7) ^ ((tid >> 3) & 7)) * 8);
    const bf16* gK = Kbase + (size_t)(tid >> 3) * DEMBED + xcol;
    const bf16* gV = Vbase + (size_t)(tid >> 3) * SLEN + xcol;

    const int swz = l31 & 7;             // row XOR for reads

    // per-block circular start offset (tile units, 0..31)
    const int off = (bh * 5 + blockIdx.y * 11) & 31;

    auto STAGE = [&](int buf, int kb) {
        char* lk = (char*)KsA + buf * 8192 + wave * 1024;
        char* lv = (char*)VsA + buf * 8192 + wave * 1024;
        gl2lds16(gK + (size_t)kb * DEMBED, lk);
        gl2lds16(gK + (size_t)(kb + 32) * DEMBED, lk + 32 * 128);
        gl2lds16(gV + kb, lv);
        gl2lds16(gV + 32 * SLEN + kb, lv + 32 * 128);
    };

    // prologue: stage tile `off` into buffer 0
    STAGE(0, off << 6);
    __syncthreads();

    int cur = 0;
    for (int ss = 0; ss < 32; ++ss) {
        // prefetch next circular tile into the other buffer
        if (ss < 31) STAGE(cur ^ 1, ((ss + off + 1) & 31) << 6);

        const char* Kbuf = (const char*)KsA + cur * 8192;
        const char* Vbuf = (const char*)VsA + cur * 8192;

        // ---- QK^T (swapped): s = mfma(A=K, B=Q) -> S^T[key][q]
        f32x16 s0 = {}, s1 = {};
#pragma unroll
        for (int ks = 0; ks < 4; ks++) {
            bf16x8 kf0 = *(const bf16x8*)(Kbuf + l31 * 128
                          + (((2 * ks + H) ^ swz) * 16));
            bf16x8 kf1 = *(const bf16x8*)(Kbuf + (32 + l31) * 128
                          + (((2 * ks + H) ^ swz) * 16));
            s0 = mfma32(kf0, qf[ks], s0);
            s1 = mfma32(kf1, qf[ks], s1);
        }

        // ---- softmax (no max-sub; scale pre-folded into Q) + pack to bf16 pairs
        int c0[8], c1[8];
#pragma unroll
        for (int t = 0; t < 8; t++) {
            float a0 = __builtin_amdgcn_exp2f(s0[2 * t]);
            float a1 = __builtin_amdgcn_exp2f(s0[2 * t + 1]);
            float b0 = __builtin_amdgcn_exp2f(s1[2 * t]);
            float b1 = __builtin_amdgcn_exp2f(s1[2 * t + 1]);
            lsv += (a0 + a1) + (b0 + b1);
            union { bf16x2 h; int i; } p0, p1;
            p0.h[0] = (bf16)a0; p0.h[1] = (bf16)a1;
            p1.h[0] = (bf16)b0; p1.h[1] = (bf16)b1;
            c0[t] = p0.i;
            c1[t] = p1.i;
        }

        // ---- PV: o[dg] += mfma(A=P, B=V).  A-frag assembled in-register:
#pragma unroll
        for (int ks = 0; ks < 4; ks++) {
            const int* cc = (ks < 2) ? c0 : c1;
            const int ksl = ks & 1;
            auto w0 = __builtin_amdgcn_permlane32_swap(cc[4 * ksl + 0],
                                                       cc[4 * ksl + 2], false, false);
            auto w1 = __builtin_amdgcn_permlane32_swap(cc[4 * ksl + 1],
                                                       cc[4 * ksl + 3], false, false);
            union { int i[4]; bf16x8 v; } ap;
            ap.i[0] = w0[0]; ap.i[1] = w1[0]; ap.i[2] = w0[1]; ap.i[3] = w1[1];
#pragma unroll
            for (int dg = 0; dg < 2; dg++) {
                bf16x8 vf = *(const bf16x8*)(Vbuf + (dg * 32 + l31) * 128
                              + (((2 * ks + H) ^ swz) * 16));
                o[dg] = mfma32(ap.v, vf, o[dg]);
            }
        }

        __syncthreads();   // drains prefetch (vmcnt0) + protects buffer reuse
        cur ^= 1;
    }

    // ---- epilogue: softmax denominator + normalized store
    lsv += __shfl_xor(lsv, 32);
    float inv = 1.0f / lsv;      // valid for q = l31 in both halves
#pragma unroll
    for (int r = 0; r < 16; r++) {
        const int ql = (r & 3) + 8 * (r >> 2) + 4 * H;
        float iv = __shfl(inv, ql);
#pragma unroll
        for (int dg = 0; dg < 2; dg++)
            O[(rowbase + qb + ql) * DEMBED + hc + dg * 32 + l31] =
                (bf16)(o[dg][r] * iv);
    }
}

// ---------------------------------------------------------------- launch
extern "C" void kernel_launch(void* const* d_in, const int* in_sizes, int n_in,
                              void* d_out, int out_size, void* d_ws, size_t ws_size,
                              hipStream_t stream) {
    const float* x  = (const float*)d_in[0];
    const float* y  = (const float*)d_in[1];
    const float* Wq = (const float*)d_in[2];
    const float* bq = (const float*)d_in[3];
    const float* Wk = (const float*)d_in[4];
    const float* bk = (const float*)d_in[5];
    const float* Wv = (const float*)d_in[6];
    const float* bv = (const float*)d_in[7];
    const float* Wo = (const float*)d_in[8];
    const float* bo = (const float*)d_in[9];
    float* out = (float*)d_out;

    char* ws = (char*)d_ws;
    size_t off = 0;
    auto alloc = [&](size_t bytes) {
        void* p = ws + off;
        off += (bytes + 255) & ~(size_t)255;
        return p;
    };
    bf16* xb  = (bf16*)alloc((size_t)MROWS * DEMBED * 2);
    bf16* yb  = (bf16*)alloc((size_t)MROWS * DCROSS * 2);
    bf16* Wqt = (bf16*)alloc((size_t)DEMBED * DEMBED * 2);
    bf16* Wkt = (bf16*)alloc((size_t)DEMBED * DCROSS * 2);
    bf16* Wvt = (bf16*)alloc((size_t)DEMBED * DCROSS * 2);
    bf16* Wot = (bf16*)alloc((size_t)DEMBED * DEMBED * 2);
    bf16* Qb  = (bf16*)alloc((size_t)MROWS * DEMBED * 2);
    bf16* Kb  = (bf16*)alloc((size_t)MROWS * DEMBED * 2);
    bf16* Vtb = (bf16*)alloc((size_t)MROWS * DEMBED * 2);  // V^T per head
    bf16* Ab  = (bf16*)alloc((size_t)MROWS * DEMBED * 2);
    if (off > ws_size) return;

    {
        PrepArgs a;
        a.wsrc[0] = Wq; a.wdst[0] = Wqt; a.wK[0] = DEMBED;
        a.wsrc[1] = Wk; a.wdst[1] = Wkt; a.wK[1] = DCROSS;
        a.wsrc[2] = Wv; a.wdst[2] = Wvt; a.wK[2] = DCROSS;
        a.wsrc[3] = Wo; a.wdst[3] = Wot; a.wK[3] = DEMBED;
        a.x = x; a.y = y; a.xb = xb; a.yb = yb;
        int ncvt = (MROWS * DEMBED / 4 + MROWS * DCROSS / 4 + 255) / 256;
        prep_all<<<NTRB + ncvt, 256, 0, stream>>>(a);
    }

    {
        QkvArgs a;
        a.xb = xb; a.yb = yb; a.Wqt = Wqt; a.Wkt = Wkt; a.Wvt = Wvt;
        a.bq = bq; a.bk = bk; a.bv = bv;
        a.Qb = Qb; a.Kb = Kb; a.Vt = Vtb;
        a.qscale = 0.125f * 1.4426950408889634f;   // 1/sqrt(64) * log2(e)
        gemm_qkv<<<1536, 256, 0, stream>>>(a);
    }

    attn<<<dim3(BATCH * NHEADS, SLEN / 128), 256, 0, stream>>>(Qb, Kb, Vtb, Ab);

    gemm_o<<<dim3(MROWS / 128, DEMBED / 128), 256, 0, stream>>>(Ab, Wot, bo, out);
}

// Round 9
// 280.617 us; speedup vs baseline: 1.0745x; 1.0070x over previous
//
#include <hip/hip_runtime.h>

#define NHEADS 16
#define DEMBED 1024
#define DCROSS 768
#define DHEAD  64
#define BATCH  4
#define SLEN   2048
#define MROWS  (BATCH * SLEN)   // 8192

using bf16   = __bf16;
using bf16x8 = __attribute__((ext_vector_type(8))) __bf16;
using bf16x4 = __attribute__((ext_vector_type(4))) __bf16;
using bf16x2 = __attribute__((ext_vector_type(2))) __bf16;
using f32x4  = __attribute__((ext_vector_type(4))) float;
using f32x16 = __attribute__((ext_vector_type(16))) float;

__device__ __forceinline__ f32x4 mfma_bf16(bf16x8 a, bf16x8 b, f32x4 c) {
    return __builtin_amdgcn_mfma_f32_16x16x32_bf16(a, b, c, 0, 0, 0);
}
__device__ __forceinline__ f32x16 mfma32(bf16x8 a, bf16x8 b, f32x16 c) {
    return __builtin_amdgcn_mfma_f32_32x32x16_bf16(a, b, c, 0, 0, 0);
}

// async global->LDS, 16B per lane; lds dest = wave-uniform base + lane*16
__device__ __forceinline__ void gl2lds16(const void* g, void* l) {
    __builtin_amdgcn_global_load_lds(
        (const __attribute__((address_space(1))) void*)g,
        (__attribute__((address_space(3))) void*)l, 16, 0, 0);
}

// ---------------------------------------------------------------- prep (one kernel)
struct PrepArgs {
    const float* wsrc[4]; bf16* wdst[4]; int wK[4];
    const float *x, *y; bf16 *xb, *yb;
};
#define NTRB 4096
__global__ void prep_all(PrepArgs a) {
    const int bid = blockIdx.x;
    const int tid = threadIdx.x;
    if (bid < NTRB) {
        __shared__ float tile[32][33];
        const int which = bid >> 10, rem = bid & 1023;
        const int K = a.wK[which], N = DEMBED;
        const int n0 = (rem & 31) * 32, k0 = (rem >> 5) * 32;
        if (k0 >= K) return;
        const float* W = a.wsrc[which];
        bf16* Wt = a.wdst[which];
        const int tx = tid & 31, ty = tid >> 5;
#pragma unroll
        for (int i = 0; i < 32; i += 8)
            tile[ty + i][tx] = W[(size_t)(k0 + ty + i) * N + n0 + tx];
        __syncthreads();
#pragma unroll
        for (int i = 0; i < 32; i += 8)
            Wt[(size_t)(n0 + ty + i) * K + k0 + tx] = (bf16)tile[tx][ty + i];
    } else {
        const int n4x = MROWS * DEMBED / 4;
        const int n4y = MROWS * DCROSS / 4;
        int i = (bid - NTRB) * 256 + tid;
        const float* src; bf16* dst; int j;
        if (i < n4x) { src = a.x; dst = a.xb; j = i; }
        else { j = i - n4x; if (j >= n4y) return; src = a.y; dst = a.yb; }
        float4 v = ((const float4*)src)[j];
        bf16x4 o = { (bf16)v.x, (bf16)v.y, (bf16)v.z, (bf16)v.w };
        ((bf16x4*)dst)[j] = o;
    }
}

// ---------------------------------------------------------------- fused QKV GEMM (r15)
// blocks [0,512): Q = xb@Wqt^T (classic 128^2 loop).
// blocks [512,1024): FUSED K+V at (yb-tile m0, embed-tile n0): stage
// {yb, Wkt, Wvt} (48 KB), yb fragments reused in BOTH MFMA roles:
//   accK[fr][fc] = mfma(yf[fr], kf[fc])   -> Kb[m0...][n0...]
//   accV[fr][fc] = mfma(vf[fr], yf[fc])   -> Vt[n0...][m0...]  (per-head ^T)
// 64 MFMAs per barrier-pair on 12 staged loads (vs 32 on 16 in two blocks).
struct QkvArgs {
    const bf16 *xb, *yb, *Wqt, *Wkt, *Wvt;
    const float *bq, *bk, *bv;
    bf16 *Qb, *Kb, *Vt;
    float qscale;
};
__global__ __launch_bounds__(256, 2) void gemm_qkv(QkvArgs a) {
    __shared__ bf16 Ys[128 * 64];   // xb/yb tile
    __shared__ bf16 Ks[128 * 64];   // Wqt/Wkt tile
    __shared__ bf16 Vs[128 * 64];   // Wvt tile (KV class only)

    const int id = blockIdx.x;
    const int tid  = threadIdx.x;
    const int wave = tid >> 6, lane = tid & 63;
    const int quad = lane >> 4, l15 = lane & 15;
    const int wr = wave >> 1, wc = wave & 1;

    const int srow = wave * 8 + (lane >> 3);
    const int scol = ((lane & 7) ^ (lane >> 3)) * 8;
    char* ldsY0 = (char*)Ys + wave * 1024;
    char* ldsK0 = (char*)Ks + wave * 1024;
    char* ldsV0 = (char*)Vs + wave * 1024;
    const int sw = l15 & 7;

    if (id < 512) {
        // ---------------- Q class: classic 128^2 loop ----------------
        const int t = id;
        const int m0 = (t >> 3) * 128, n0 = (t & 7) * 128;
        const int K = DEMBED;
        const bf16* gA0 = a.xb + (size_t)(m0 + srow) * K + scol;
        const bf16* gB0 = a.Wqt + (size_t)(n0 + srow) * K + scol;

        f32x4 acc[4][4] = {};

        for (int kt = 0; kt < K; kt += 64) {
            __syncthreads();
#pragma unroll
            for (int c = 0; c < 4; c++)
                gl2lds16(gA0 + (size_t)c * 32 * K + kt, ldsY0 + c * 4096);
#pragma unroll
            for (int c = 0; c < 4; c++)
                gl2lds16(gB0 + (size_t)c * 32 * K + kt, ldsK0 + c * 4096);
            __syncthreads();

#pragma unroll
            for (int kg = 0; kg < 2; kg++) {
                bf16x8 af[4], bfr[4];
#pragma unroll
                for (int i = 0; i < 4; i++)
                    af[i] = *(const bf16x8*)((const char*)Ys +
                             (wr * 64 + i * 16 + l15) * 128 + (((kg * 4 + quad) ^ sw) * 16));
#pragma unroll
                for (int i = 0; i < 4; i++)
                    bfr[i] = *(const bf16x8*)((const char*)Ks +
                             (wc * 64 + i * 16 + l15) * 128 + (((kg * 4 + quad) ^ sw) * 16));
#pragma unroll
                for (int fr = 0; fr < 4; fr++)
#pragma unroll
                    for (int fc = 0; fc < 4; fc++)
                        acc[fr][fc] = mfma_bf16(af[fr], bfr[fc], acc[fr][fc]);
            }
        }

        const float alpha = a.qscale;
#pragma unroll
        for (int fr = 0; fr < 4; fr++) {
            int row = m0 + wr * 64 + fr * 16 + quad * 4;
#pragma unroll
            for (int fc = 0; fc < 4; fc++) {
                int col = n0 + wc * 64 + fc * 16 + l15;
                float bv = a.bq[col];
#pragma unroll
                for (int r = 0; r < 4; r++)
                    a.Qb[(size_t)(row + r) * DEMBED + col] =
                        (bf16)((acc[fr][fc][r] + bv) * alpha);
            }
        }
    } else {
        // ---------------- fused K+V class ----------------
        const int t = id - 512;
        const int m0 = (t >> 3) * 128;   // over MROWS (64 tiles)
        const int n0 = (t & 7) * 128;    // over DEMBED (8 tiles)
        const int K = DCROSS;            // 768
        const bf16* gY = a.yb  + (size_t)(m0 + srow) * K + scol;
        const bf16* gK = a.Wkt + (size_t)(n0 + srow) * K + scol;
        const bf16* gV = a.Wvt + (size_t)(n0 + srow) * K + scol;

        f32x4 accK[4][4] = {};
        f32x4 accV[4][4] = {};

        for (int kt = 0; kt < K; kt += 64) {
            __syncthreads();
#pragma unroll
            for (int c = 0; c < 4; c++)
                gl2lds16(gY + (size_t)c * 32 * K + kt, ldsY0 + c * 4096);
#pragma unroll
            for (int c = 0; c < 4; c++)
                gl2lds16(gK + (size_t)c * 32 * K + kt, ldsK0 + c * 4096);
#pragma unroll
            for (int c = 0; c < 4; c++)
                gl2lds16(gV + (size_t)c * 32 * K + kt, ldsV0 + c * 4096);
            __syncthreads();

#pragma unroll
            for (int kg = 0; kg < 2; kg++) {
                bf16x8 yf[4], kf[4], vf[4];
#pragma unroll
                for (int i = 0; i < 4; i++)
                    yf[i] = *(const bf16x8*)((const char*)Ys +
                             (wr * 64 + i * 16 + l15) * 128 + (((kg * 4 + quad) ^ sw) * 16));
#pragma unroll
                for (int i = 0; i < 4; i++)
                    kf[i] = *(const bf16x8*)((const char*)Ks +
                             (wc * 64 + i * 16 + l15) * 128 + (((kg * 4 + quad) ^ sw) * 16));
#pragma unroll
                for (int i = 0; i < 4; i++)
                    vf[i] = *(const bf16x8*)((const char*)Vs +
                             (wc * 64 + i * 16 + l15) * 128 + (((kg * 4 + quad) ^ sw) * 16));
                __builtin_amdgcn_s_setprio(1);
#pragma unroll
                for (int fr = 0; fr < 4; fr++)
#pragma unroll
                    for (int fc = 0; fc < 4; fc++)
                        accK[fr][fc] = mfma_bf16(yf[fr], kf[fc], accK[fr][fc]);
#pragma unroll
                for (int fr = 0; fr < 4; fr++)
#pragma unroll
                    for (int fc = 0; fc < 4; fc++)
                        accV[fr][fc] = mfma_bf16(vf[fr], yf[fc], accV[fr][fc]);
                __builtin_amdgcn_s_setprio(0);
            }
        }

        // K epilogue: rows over MROWS, cols over DEMBED
#pragma unroll
        for (int fr = 0; fr < 4; fr++) {
            int row = m0 + wr * 64 + fr * 16 + quad * 4;
#pragma unroll
            for (int fc = 0; fc < 4; fc++) {
                int col = n0 + wc * 64 + fc * 16 + l15;
                float bv = a.bk[col];
#pragma unroll
                for (int r = 0; r < 4; r++)
                    a.Kb[(size_t)(row + r) * DEMBED + col] =
                        (bf16)(accK[fr][fc][r] + bv);
            }
        }
        // V epilogue: C_v[row_v over DEMBED][col_v over MROWS] -> Vt per-head ^T
        const int b = m0 >> 11;                      // batch of this yb tile
        const size_t bbase = (size_t)b * DEMBED * SLEN;
#pragma unroll
        for (int fr = 0; fr < 4; fr++) {
            int row_v = n0 + wc * 64 + fr * 16 + quad * 4;
#pragma unroll
            for (int fc = 0; fc < 4; fc++) {
                int col_v = m0 + wr * 64 + fc * 16 + l15;
                int s = col_v & (SLEN - 1);
#pragma unroll
                for (int r = 0; r < 4; r++)
                    a.Vt[bbase + (size_t)(row_v + r) * SLEN + s] =
                        (bf16)(accV[fr][fc][r] + a.bv[row_v + r]);
            }
        }
    }
}

// ---------------------------------------------------------------- O GEMM (r6 128^2)
__global__ __launch_bounds__(256, 3) void gemm_o(const bf16* __restrict__ A,
                                                 const bf16* __restrict__ Bt,
                                                 const float* __restrict__ bias,
                                                 float* __restrict__ Cout) {
    const int K = DEMBED, N = DEMBED;
    __shared__ bf16 As[128 * 64];
    __shared__ bf16 Bs[128 * 64];
    const int tid  = threadIdx.x;
    const int wave = tid >> 6, lane = tid & 63;
    const int quad = lane >> 4, l15 = lane & 15;
    const int m0 = blockIdx.x * 128, n0 = blockIdx.y * 128;
    const int wr = wave >> 1, wc = wave & 1;

    const int srow = wave * 8 + (lane >> 3);
    const int scol = ((lane & 7) ^ (lane >> 3)) * 8;
    char* ldsA0 = (char*)As + wave * 1024;
    char* ldsB0 = (char*)Bs + wave * 1024;
    const bf16* gA0 = A + (size_t)(m0 + srow) * K + scol;
    const bf16* gB0 = Bt + (size_t)(n0 + srow) * K + scol;

    const int sw = l15 & 7;

    f32x4 acc[4][4] = {};

    for (int kt = 0; kt < K; kt += 64) {
        __syncthreads();
#pragma unroll
        for (int c = 0; c < 4; c++)
            gl2lds16(gA0 + (size_t)c * 32 * K + kt, ldsA0 + c * 4096);
#pragma unroll
        for (int c = 0; c < 4; c++)
            gl2lds16(gB0 + (size_t)c * 32 * K + kt, ldsB0 + c * 4096);
        __syncthreads();

#pragma unroll
        for (int kg = 0; kg < 2; kg++) {
            bf16x8 af[4], bfr[4];
#pragma unroll
            for (int i = 0; i < 4; i++)
                af[i] = *(const bf16x8*)((const char*)As +
                         (wr * 64 + i * 16 + l15) * 128 + (((kg * 4 + quad) ^ sw) * 16));
#pragma unroll
            for (int i = 0; i < 4; i++)
                bfr[i] = *(const bf16x8*)((const char*)Bs +
                         (wc * 64 + i * 16 + l15) * 128 + (((kg * 4 + quad) ^ sw) * 16));
#pragma unroll
            for (int fr = 0; fr < 4; fr++)
#pragma unroll
                for (int fc = 0; fc < 4; fc++)
                    acc[fr][fc] = mfma_bf16(af[fr], bfr[fc], acc[fr][fc]);
        }
    }

#pragma unroll
    for (int fr = 0; fr < 4; fr++) {
        int row = m0 + wr * 64 + fr * 16 + quad * 4;
#pragma unroll
        for (int fc = 0; fc < 4; fc++) {
            int col = n0 + wc * 64 + fc * 16 + l15;
            float bv = bias[col];
#pragma unroll
            for (int r = 0; r < 4; r++)
                Cout[(size_t)(row + r) * N + col] = acc[fr][fc][r] + bv;
        }
    }
}

// ---------------------------------------------------------------- attention (r14 stagger, kept)
__global__ __launch_bounds__(256, 4) void attn(const bf16* __restrict__ Q,
                                               const bf16* __restrict__ K,
                                               const bf16* __restrict__ Vt,
                                               bf16* __restrict__ O) {
    __shared__ bf16 KsA[2][64 * 64];     // [buf][key][d]   XOR-swizzled slots
    __shared__ bf16 VsA[2][64 * 64];     // [buf][d][key]   XOR-swizzled slots

    const int tid  = threadIdx.x;
    const int wave = tid >> 6, lane = tid & 63;
    const int l31  = lane & 31, H = lane >> 5;
    const int bh = blockIdx.x, b = bh >> 4, h = bh & 15;
    const size_t rowbase = (size_t)b * SLEN;
    const int qb = blockIdx.y * 128 + wave * 32;
    const int hc = h * DHEAD;

    bf16x8 qf[4];
#pragma unroll
    for (int ks = 0; ks < 4; ks++)
        qf[ks] = *(const bf16x8*)(Q + (rowbase + qb + l31) * DEMBED
                                  + hc + ks * 16 + H * 8);

    f32x16 o[2] = {};
    float lsv = 0.0f;

    const bf16* Kbase = K + rowbase * DEMBED + hc;
    const bf16* Vbase = Vt + (size_t)bh * DHEAD * SLEN;

    const int xcol = (((tid & 7) ^ ((tid >> 3) & 7)) * 8);
    const bf16* gK = Kbase + (size_t)(tid >> 3) * DEMBED + xcol;
    const bf16* gV = Vbase + (size_t)(tid >> 3) * SLEN + xcol;

    const int swz = l31 & 7;             // row XOR for reads

    // per-block circular start offset (tile units, 0..31)
    const int off = (bh * 5 + blockIdx.y * 11) & 31;

    auto STAGE = [&](int buf, int kb) {
        char* lk = (char*)KsA + buf * 8192 + wave * 1024;
        char* lv = (char*)VsA + buf * 8192 + wave * 1024;
        gl2lds16(gK + (size_t)kb * DEMBED, lk);
        gl2lds16(gK + (size_t)(kb + 32) * DEMBED, lk + 32 * 128);
        gl2lds16(gV + kb, lv);
        gl2lds16(gV + 32 * SLEN + kb, lv + 32 * 128);
    };

    STAGE(0, off << 6);
    __syncthreads();

    int cur = 0;
    for (int ss = 0; ss < 32; ++ss) {
        if (ss < 31) STAGE(cur ^ 1, ((ss + off + 1) & 31) << 6);

        const char* Kbuf = (const char*)KsA + cur * 8192;
        const char* Vbuf = (const char*)VsA + cur * 8192;

        // ---- QK^T (swapped): s = mfma(A=K, B=Q) -> S^T[key][q]
        f32x16 s0 = {}, s1 = {};
#pragma unroll
        for (int ks = 0; ks < 4; ks++) {
            bf16x8 kf0 = *(const bf16x8*)(Kbuf + l31 * 128
                          + (((2 * ks + H) ^ swz) * 16));
            bf16x8 kf1 = *(const bf16x8*)(Kbuf + (32 + l31) * 128
                          + (((2 * ks + H) ^ swz) * 16));
            s0 = mfma32(kf0, qf[ks], s0);
            s1 = mfma32(kf1, qf[ks], s1);
        }

        // ---- softmax (no max-sub; scale pre-folded into Q) + pack to bf16 pairs
        int c0[8], c1[8];
#pragma unroll
        for (int t = 0; t < 8; t++) {
            float a0 = __builtin_amdgcn_exp2f(s0[2 * t]);
            float a1 = __builtin_amdgcn_exp2f(s0[2 * t + 1]);
            float b0 = __builtin_amdgcn_exp2f(s1[2 * t]);
            float b1 = __builtin_amdgcn_exp2f(s1[2 * t + 1]);
            lsv += (a0 + a1) + (b0 + b1);
            union { bf16x2 h; int i; } p0, p1;
            p0.h[0] = (bf16)a0; p0.h[1] = (bf16)a1;
            p1.h[0] = (bf16)b0; p1.h[1] = (bf16)b1;
            c0[t] = p0.i;
            c1[t] = p1.i;
        }

        // ---- PV: o[dg] += mfma(A=P, B=V).  A-frag assembled in-register:
#pragma unroll
        for (int ks = 0; ks < 4; ks++) {
            const int* cc = (ks < 2) ? c0 : c1;
            const int ksl = ks & 1;
            auto w0 = __builtin_amdgcn_permlane32_swap(cc[4 * ksl + 0],
                                                       cc[4 * ksl + 2], false, false);
            auto w1 = __builtin_amdgcn_permlane32_swap(cc[4 * ksl + 1],
                                                       cc[4 * ksl + 3], false, false);
            union { int i[4]; bf16x8 v; } ap;
            ap.i[0] = w0[0]; ap.i[1] = w1[0]; ap.i[2] = w0[1]; ap.i[3] = w1[1];
#pragma unroll
            for (int dg = 0; dg < 2; dg++) {
                bf16x8 vf = *(const bf16x8*)(Vbuf + (dg * 32 + l31) * 128
                              + (((2 * ks + H) ^ swz) * 16));
                o[dg] = mfma32(ap.v, vf, o[dg]);
            }
        }

        __syncthreads();   // drains prefetch (vmcnt0) + protects buffer reuse
        cur ^= 1;
    }

    lsv += __shfl_xor(lsv, 32);
    float inv = 1.0f / lsv;
#pragma unroll
    for (int r = 0; r < 16; r++) {
        const int ql = (r & 3) + 8 * (r >> 2) + 4 * H;
        float iv = __shfl(inv, ql);
#pragma unroll
        for (int dg = 0; dg < 2; dg++)
            O[(rowbase + qb + ql) * DEMBED + hc + dg * 32 + l31] =
                (bf16)(o[dg][r] * iv);
    }
}

// ---------------------------------------------------------------- launch
extern "C" void kernel_launch(void* const* d_in, const int* in_sizes, int n_in,
                              void* d_out, int out_size, void* d_ws, size_t ws_size,
                              hipStream_t stream) {
    const float* x  = (const float*)d_in[0];
    const float* y  = (const float*)d_in[1];
    const float* Wq = (const float*)d_in[2];
    const float* bq = (const float*)d_in[3];
    const float* Wk = (const float*)d_in[4];
    const float* bk = (const float*)d_in[5];
    const float* Wv = (const float*)d_in[6];
    const float* bv = (const float*)d_in[7];
    const float* Wo = (const float*)d_in[8];
    const float* bo = (const float*)d_in[9];
    float* out = (float*)d_out;

    char* ws = (char*)d_ws;
    size_t off = 0;
    auto alloc = [&](size_t bytes) {
        void* p = ws + off;
        off += (bytes + 255) & ~(size_t)255;
        return p;
    };
    bf16* xb  = (bf16*)alloc((size_t)MROWS * DEMBED * 2);
    bf16* yb  = (bf16*)alloc((size_t)MROWS * DCROSS * 2);
    bf16* Wqt = (bf16*)alloc((size_t)DEMBED * DEMBED * 2);
    bf16* Wkt = (bf16*)alloc((size_t)DEMBED * DCROSS * 2);
    bf16* Wvt = (bf16*)alloc((size_t)DEMBED * DCROSS * 2);
    bf16* Wot = (bf16*)alloc((size_t)DEMBED * DEMBED * 2);
    bf16* Qb  = (bf16*)alloc((size_t)MROWS * DEMBED * 2);
    bf16* Kb  = (bf16*)alloc((size_t)MROWS * DEMBED * 2);
    bf16* Vtb = (bf16*)alloc((size_t)MROWS * DEMBED * 2);  // V^T per head
    bf16* Ab  = (bf16*)alloc((size_t)MROWS * DEMBED * 2);
    if (off > ws_size) return;

    {
        PrepArgs a;
        a.wsrc[0] = Wq; a.wdst[0] = Wqt; a.wK[0] = DEMBED;
        a.wsrc[1] = Wk; a.wdst[1] = Wkt; a.wK[1] = DCROSS;
        a.wsrc[2] = Wv; a.wdst[2] = Wvt; a.wK[2] = DCROSS;
        a.wsrc[3] = Wo; a.wdst[3] = Wot; a.wK[3] = DEMBED;
        a.x = x; a.y = y; a.xb = xb; a.yb = yb;
        int ncvt = (MROWS * DEMBED / 4 + MROWS * DCROSS / 4 + 255) / 256;
        prep_all<<<NTRB + ncvt, 256, 0, stream>>>(a);
    }

    {
        QkvArgs a;
        a.xb = xb; a.yb = yb; a.Wqt = Wqt; a.Wkt = Wkt; a.Wvt = Wvt;
        a.bq = bq; a.bk = bk; a.bv = bv;
        a.Qb = Qb; a.Kb = Kb; a.Vt = Vtb;
        a.qscale = 0.125f * 1.4426950408889634f;   // 1/sqrt(64) * log2(e)
        gemm_qkv<<<1024, 256, 0, stream>>>(a);
    }

    attn<<<dim3(BATCH * NHEADS, SLEN / 128), 256, 0, stream>>>(Qb, Kb, Vtb, Ab);

    gemm_o<<<dim3(MROWS / 128, DEMBED / 128), 256, 0, stream>>>(Ab, Wot, bo, out);
}